// Round 1
// baseline (409.706 us; speedup 1.0000x reference)
//
#include <hip/hip_runtime.h>
#include <hip/hip_bf16.h>

// mLSTM parallel-stabilized cell, MI355X (gfx950).
// B=2, S=2048, H=1024, NH=4, DH=256.
// Key identity: max_log_D[i] = cs[i] + m[i] with m[i] = prefixmax(ig[j]-cs[j]),
// so D[i][j] = exp(a[j]-m[i]) with a[j]=ig[j]-cs[j]; exponent always <= 0.

#define S_LEN 2048
#define DHD   256
#define NHEAD 4
#define BATCH 2
#define HID   1024
#define BH_CNT (BATCH*NHEAD)

typedef __attribute__((ext_vector_type(8))) short bf16x8;
typedef __attribute__((ext_vector_type(4))) short short4v;
typedef __attribute__((ext_vector_type(4))) float f32x4;

static __device__ __forceinline__ short f2b(float f) {
  __hip_bfloat16 h = __float2bfloat16(f);
  return *reinterpret_cast<short*>(&h);
}

// ---- kernel 1: cast (B,S,H) fp32 -> per-head bf16 [(b,h), S, DH] ----
__global__ void cast_heads_kernel(const float* __restrict__ in, short* __restrict__ out) {
  long lin = ((long)blockIdx.x * blockDim.x + threadIdx.x) * 8;
  int d = (int)(lin % DHD);
  long r = lin / DHD;
  int s  = (int)(r % S_LEN);
  int bh = (int)(r / S_LEN);
  int b = bh >> 2, h = bh & 3;
  const float* src = in + ((long)(b*S_LEN + s))*HID + h*DHD + d;
  f32x4 v0 = *(const f32x4*)(src);
  f32x4 v1 = *(const f32x4*)(src + 4);
  bf16x8 o;
  o[0]=f2b(v0[0]); o[1]=f2b(v0[1]); o[2]=f2b(v0[2]); o[3]=f2b(v0[3]);
  o[4]=f2b(v1[0]); o[5]=f2b(v1[1]); o[6]=f2b(v1[2]); o[7]=f2b(v1[3]);
  *(bf16x8*)(out + lin) = o;
}

// ---- kernel 2: v (B,S,H) fp32 -> VT bf16 [(b,h), DH, S] (LDS-tiled transpose) ----
__global__ void transpose_v_kernel(const float* __restrict__ v, short* __restrict__ vt) {
  __shared__ short tile[32][33];
  int d0 = blockIdx.x * 32, j0 = blockIdx.y * 32, bh = blockIdx.z;
  int b = bh >> 2, h = bh & 3;
  int c = threadIdx.x & 31, rr = threadIdx.x >> 5;
  for (int kk = 0; kk < 32; kk += 8)
    tile[rr + kk][c] = f2b(v[((long)(b*S_LEN + j0 + rr + kk))*HID + h*DHD + d0 + c]);
  __syncthreads();
  for (int kk = 0; kk < 32; kk += 8)
    vt[((long)bh*DHD + d0 + rr + kk)*S_LEN + j0 + c] = tile[c][rr + kk];
}

// ---- kernel 3: gate projections ig/fg = [q|k|v] @ W + b  (one wave per row) ----
__global__ void gate_kernel(const float* __restrict__ q, const float* __restrict__ k,
                            const float* __restrict__ v,
                            const float* __restrict__ wi, const float* __restrict__ bi,
                            const float* __restrict__ wf, const float* __restrict__ bf_,
                            float* __restrict__ ig, float* __restrict__ fg) {
  int row = blockIdx.x * 4 + (threadIdx.x >> 6);   // b*S + s
  int lane = threadIdx.x & 63;
  f32x4 ai = {0.f,0.f,0.f,0.f}, af = {0.f,0.f,0.f,0.f};
  long rbase = (long)row * HID;
  for (int c = lane; c < 3*HID; c += 64) {
    int p = c >> 10, idx = c & (HID-1);
    float x = (p == 0 ? q[rbase + idx] : (p == 1 ? k[rbase + idx] : v[rbase + idx]));
    f32x4 w4i = *(const f32x4*)(wi + (long)c*NHEAD);
    f32x4 w4f = *(const f32x4*)(wf + (long)c*NHEAD);
    ai += x * w4i;
    af += x * w4f;
  }
  for (int mk = 32; mk >= 1; mk >>= 1) {
    for (int e = 0; e < 4; e++) {
      ai[e] += __shfl_xor(ai[e], mk);
      af[e] += __shfl_xor(af[e], mk);
    }
  }
  if (lane == 0) {
    for (int e = 0; e < 4; e++) {
      ig[(long)row*NHEAD + e] = ai[e] + bi[e];
      fg[(long)row*NHEAD + e] = af[e] + bf_[e];
    }
  }
}

// ---- kernel 4: per-(b,h) scan: cs = cumsum(logsigmoid(fg)); a = ig - cs;
//      m = prefixmax(a); nfloor = exp(-(cs+m)) ----
__global__ void scan_kernel(const float* __restrict__ ig, const float* __restrict__ fg,
                            float* __restrict__ a_out, float* __restrict__ m_out,
                            float* __restrict__ nf_out) {
  int bh = blockIdx.x, b = bh >> 2, h = bh & 3;
  int t = threadIdx.x;
  __shared__ float tot[256];
  long gbase = (long)b * S_LEN;
  float ls[8];
  float run = 0.f;
  for (int e = 0; e < 8; e++) {
    int s = t*8 + e;
    float x = fg[(gbase + s)*NHEAD + h];
    float l = fminf(x, 0.f) - log1pf(expf(-fabsf(x)));  // stable log_sigmoid
    run += l; ls[e] = run;
  }
  tot[t] = run;
  __syncthreads();
  if (t == 0) { float acc = 0.f; for (int i = 0; i < 256; i++) { float tmp = tot[i]; tot[i] = acc; acc += tmp; } }
  __syncthreads();
  float offc = tot[t];
  float av[8], am[8], csv[8];
  float runm = -1e30f;
  for (int e = 0; e < 8; e++) {
    int s = t*8 + e;
    float cs = ls[e] + offc;
    csv[e] = cs;
    float a = ig[(gbase + s)*NHEAD + h] - cs;
    av[e] = a;
    runm = fmaxf(runm, a);
    am[e] = runm;
  }
  __syncthreads();
  tot[t] = runm;
  __syncthreads();
  if (t == 0) { float acc = -1e30f; for (int i = 0; i < 256; i++) { float tmp = tot[i]; tot[i] = acc; acc = fmaxf(acc, tmp); } }
  __syncthreads();
  float offm = tot[t];
  long obase = (long)bh * S_LEN;
  for (int e = 0; e < 8; e++) {
    int s = t*8 + e;
    float mm = fmaxf(am[e], offm);
    a_out[obase + s]  = av[e];
    m_out[obase + s]  = mm;
    nf_out[obase + s] = expf(-(csv[e] + mm));
  }
}

// ---- kernel 5: main flash-style causal loop + normalizer + per-head LayerNorm ----
// grid (S/64, BH), 256 threads = 4 independent waves, wave owns 16 query rows.
// MFMA 16x16x32 bf16 layouts: A[row=l&15][k=(l>>4)*8+e], B[k=(l>>4)*8+e][col=l&15],
// C/D: col=l&15, row=(l>>4)*4+reg (m89-verified).
__global__ __launch_bounds__(256) void mlstm_main_kernel(
    const short* __restrict__ Qb, const short* __restrict__ Kb, const short* __restrict__ VTb,
    const float* __restrict__ a_arr, const float* __restrict__ m_arr, const float* __restrict__ nf_arr,
    const float* __restrict__ lnscale, float* __restrict__ outp) {
  // stride 36 shorts: conflict-free P writes (18r+8g bank pattern), 8B-aligned b64 reads
  __shared__ short plds[4][16*36];
  const int w = threadIdx.x >> 6, lane = threadIdx.x & 63;
  const int lr = lane & 15, g = lane >> 4;
  const int bh = blockIdx.y, b = bh >> 2, h = bh & 3;
  const int i0 = blockIdx.x * 64 + w * 16;
  const long hq = (long)bh * S_LEN * DHD;
  const long arow = (long)bh * S_LEN;
  const f32x4 zz = {0.f,0.f,0.f,0.f};

  // preload Q fragments for this wave's 16 rows (whole DH=256)
  bf16x8 qf[8];
  const short* qptr = Qb + hq + (long)(i0 + lr) * DHD + g*8;
#pragma unroll
  for (int c = 0; c < 8; c++) qf[c] = *(const bf16x8*)(qptr + c*32);

  float mrow[4], nfl[4];
#pragma unroll
  for (int r = 0; r < 4; r++) {
    int i = i0 + g*4 + r;
    mrow[r] = m_arr[arow + i];
    nfl[r]  = nf_arr[arow + i];
  }

  f32x4 oacc[16];
#pragma unroll
  for (int t = 0; t < 16; t++) oacc[t] = zz;
  float rs[4] = {0.f,0.f,0.f,0.f};

  short* myp = plds[w];
  const int ntiles = i0/32 + 1;
  const short* kbase = Kb + hq + (long)lr * DHD + g*8;
  const short* vbase = VTb + hq + (long)lr * S_LEN + g*8;

  for (int jt = 0; jt < ntiles; jt++) {
    const int j0 = jt * 32;
    f32x4 s0 = zz, s1 = zz;
    const short* kp = kbase + (long)j0 * DHD;
#pragma unroll
    for (int c = 0; c < 8; c++) {
      bf16x8 k0 = *(const bf16x8*)(kp + c*32);
      bf16x8 k1 = *(const bf16x8*)(kp + 16*DHD + c*32);
      s0 = __builtin_amdgcn_mfma_f32_16x16x32_bf16(qf[c], k0, s0, 0, 0, 0);
      s1 = __builtin_amdgcn_mfma_f32_16x16x32_bf16(qf[c], k1, s1, 0, 0, 0);
    }
    const float a0 = a_arr[arow + j0 + lr];
    const float a1 = a_arr[arow + j0 + 16 + lr];
    const bool last = (jt == ntiles - 1);
#pragma unroll
    for (int r = 0; r < 4; r++) {
      const int i = i0 + g*4 + r;
      float p0 = s0[r] * 0.0625f * __expf(a0 - mrow[r]);
      float p1 = s1[r] * 0.0625f * __expf(a1 - mrow[r]);
      if (last) {                 // causal mask, only diagonal tile needs it
        if (j0 + lr > i)      p0 = 0.f;
        if (j0 + 16 + lr > i) p1 = 0.f;
      }
      rs[r] += p0 + p1;
      myp[(g*4 + r)*36 + lr]      = f2b(p0);
      myp[(g*4 + r)*36 + 16 + lr] = f2b(p1);
    }
    // re-fragment P (C-layout) -> A-layout via per-wave LDS (no barrier needed)
    const short* rp = myp + lr*36 + g*8;
    short4v plo = *(const short4v*)rp;
    short4v phi = *(const short4v*)(rp + 4);
    bf16x8 pa = {plo[0],plo[1],plo[2],plo[3],phi[0],phi[1],phi[2],phi[3]};
    const short* vp = vbase + j0;
#pragma unroll
    for (int t = 0; t < 16; t++) {
      bf16x8 vf = *(const bf16x8*)(vp + (long)t * 16 * S_LEN);
      oacc[t] = __builtin_amdgcn_mfma_f32_16x16x32_bf16(pa, vf, oacc[t], 0, 0, 0);
    }
  }

  // rowsum reduce across the 16 lanes sharing this row group
#pragma unroll
  for (int r = 0; r < 4; r++)
    for (int mk = 1; mk < 16; mk <<= 1)
      rs[r] += __shfl_xor(rs[r], mk);

  float inv[4];
#pragma unroll
  for (int r = 0; r < 4; r++)
    inv[r] = 1.f / (fmaxf(fabsf(rs[r]), nfl[r]) + 1e-6f);

  // normalize + LayerNorm stats
  float sum[4] = {0.f,0.f,0.f,0.f}, sq[4] = {0.f,0.f,0.f,0.f};
#pragma unroll
  for (int t = 0; t < 16; t++)
#pragma unroll
    for (int r = 0; r < 4; r++) {
      float x = oacc[t][r] * inv[r];
      oacc[t][r] = x;
      sum[r] += x; sq[r] += x*x;
    }
#pragma unroll
  for (int r = 0; r < 4; r++)
    for (int mk = 1; mk < 16; mk <<= 1) {
      sum[r] += __shfl_xor(sum[r], mk);
      sq[r]  += __shfl_xor(sq[r], mk);
    }
  float sc[16];
#pragma unroll
  for (int t = 0; t < 16; t++) sc[t] = lnscale[h*DHD + t*16 + lr];
#pragma unroll
  for (int r = 0; r < 4; r++) {
    float mean = sum[r] * (1.f/256.f);
    float var  = sq[r] * (1.f/256.f) - mean*mean;
    float rstd = rsqrtf(var + 1e-5f);
    const int i = i0 + g*4 + r;
    float* orow = outp + ((long)(b*S_LEN + i))*HID + h*DHD + lr;
#pragma unroll
    for (int t = 0; t < 16; t++)
      orow[t*16] = (oacc[t][r] - mean) * rstd * sc[t];
  }
}

extern "C" void kernel_launch(void* const* d_in, const int* in_sizes, int n_in,
                              void* d_out, int out_size, void* d_ws, size_t ws_size,
                              hipStream_t stream) {
  const float* q   = (const float*)d_in[0];
  const float* k   = (const float*)d_in[1];
  const float* v   = (const float*)d_in[2];
  const float* wi  = (const float*)d_in[3];
  const float* bi  = (const float*)d_in[4];
  const float* wf  = (const float*)d_in[5];
  const float* bf_ = (const float*)d_in[6];
  const float* lns = (const float*)d_in[7];
  float* outp = (float*)d_out;

  // workspace layout (~25.5 MB): Qb, Kb, VTb bf16 + gate/scan arrays
  char* ws = (char*)d_ws;
  const long nelem = (long)BH_CNT * S_LEN * DHD;      // 4,194,304
  short* Qb  = (short*)ws;
  short* Kb  = Qb + nelem;
  short* VTb = Kb + nelem;
  float* igA = (float*)(ws + 3*nelem*sizeof(short));
  float* fgA = igA + (long)BATCH*S_LEN*NHEAD;
  float* aA  = fgA + (long)BATCH*S_LEN*NHEAD;
  float* mA  = aA + (long)BH_CNT*S_LEN;
  float* nfA = mA + (long)BH_CNT*S_LEN;

  cast_heads_kernel<<<2048, 256, 0, stream>>>(q, Qb);
  cast_heads_kernel<<<2048, 256, 0, stream>>>(k, Kb);
  transpose_v_kernel<<<dim3(DHD/32, S_LEN/32, BH_CNT), 256, 0, stream>>>(v, VTb);
  gate_kernel<<<(BATCH*S_LEN)/4, 256, 0, stream>>>(q, k, v, wi, bi, wf, bf_, igA, fgA);
  scan_kernel<<<BH_CNT, 256, 0, stream>>>(igA, fgA, aA, mA, nfA);
  mlstm_main_kernel<<<dim3(S_LEN/64, BH_CNT), 256, 0, stream>>>(Qb, Kb, VTb, aA, mA, nfA, lns, outp);
}

// Round 2
// 249.179 us; speedup vs baseline: 1.6442x; 1.6442x over previous
//
#include <hip/hip_runtime.h>
#include <hip/hip_bf16.h>

// mLSTM parallel-stabilized cell, MI355X (gfx950).
// B=2, S=2048, H=1024, NH=4, DH=256.
// Identity: max_log_D[i] = cs[i] + m[i], m[i] = prefixmax(ig[j]-cs[j]);
// D[i][j] = exp(a[j]-m[i]), a[j] = ig[j]-cs[j]. m is GLOBAL (precomputed), so
// partial O / rowsum over disjoint key chunks are additive -> j-split blocks
// with fp32 atomic accumulation into d_out, then a finalize pass.

#define S_LEN 2048
#define DHD   256
#define NHEAD 4
#define BATCH 2
#define HID   1024
#define BH_CNT (BATCH*NHEAD)

typedef __attribute__((ext_vector_type(8))) short bf16x8;
typedef __attribute__((ext_vector_type(4))) short short4v;
typedef __attribute__((ext_vector_type(4))) float f32x4;

static __device__ __forceinline__ short f2b(float f) {
  __hip_bfloat16 h = __float2bfloat16(f);
  return *reinterpret_cast<short*>(&h);
}

// ---- kernel 1: cast (B,S,H) fp32 -> per-head bf16 [(b,h), S, DH] ----
__global__ void cast_heads_kernel(const float* __restrict__ in, short* __restrict__ out) {
  long lin = ((long)blockIdx.x * blockDim.x + threadIdx.x) * 8;
  int d = (int)(lin % DHD);
  long r = lin / DHD;
  int s  = (int)(r % S_LEN);
  int bh = (int)(r / S_LEN);
  int b = bh >> 2, h = bh & 3;
  const float* src = in + ((long)(b*S_LEN + s))*HID + h*DHD + d;
  f32x4 v0 = *(const f32x4*)(src);
  f32x4 v1 = *(const f32x4*)(src + 4);
  bf16x8 o;
  o[0]=f2b(v0[0]); o[1]=f2b(v0[1]); o[2]=f2b(v0[2]); o[3]=f2b(v0[3]);
  o[4]=f2b(v1[0]); o[5]=f2b(v1[1]); o[6]=f2b(v1[2]); o[7]=f2b(v1[3]);
  *(bf16x8*)(out + lin) = o;
}

// ---- kernel 2: v (B,S,H) fp32 -> VT bf16 [(b,h), DH, S] (LDS-tiled transpose) ----
__global__ void transpose_v_kernel(const float* __restrict__ v, short* __restrict__ vt) {
  __shared__ short tile[32][33];
  int d0 = blockIdx.x * 32, j0 = blockIdx.y * 32, bh = blockIdx.z;
  int b = bh >> 2, h = bh & 3;
  int c = threadIdx.x & 31, rr = threadIdx.x >> 5;
  for (int kk = 0; kk < 32; kk += 8)
    tile[rr + kk][c] = f2b(v[((long)(b*S_LEN + j0 + rr + kk))*HID + h*DHD + d0 + c]);
  __syncthreads();
  for (int kk = 0; kk < 32; kk += 8)
    vt[((long)bh*DHD + d0 + rr + kk)*S_LEN + j0 + c] = tile[c][rr + kk];
}

// ---- kernel 3: gate projections ig/fg = [q|k|v] @ W + b  (one wave per row) ----
__global__ void gate_kernel(const float* __restrict__ q, const float* __restrict__ k,
                            const float* __restrict__ v,
                            const float* __restrict__ wi, const float* __restrict__ bi,
                            const float* __restrict__ wf, const float* __restrict__ bf_,
                            float* __restrict__ ig, float* __restrict__ fg) {
  int row = blockIdx.x * 4 + (threadIdx.x >> 6);   // b*S + s
  int lane = threadIdx.x & 63;
  f32x4 ai = {0.f,0.f,0.f,0.f}, af = {0.f,0.f,0.f,0.f};
  long rbase = (long)row * HID;
  for (int c = lane; c < 3*HID; c += 64) {
    int p = c >> 10, idx = c & (HID-1);
    float x = (p == 0 ? q[rbase + idx] : (p == 1 ? k[rbase + idx] : v[rbase + idx]));
    f32x4 w4i = *(const f32x4*)(wi + (long)c*NHEAD);
    f32x4 w4f = *(const f32x4*)(wf + (long)c*NHEAD);
    ai += x * w4i;
    af += x * w4f;
  }
  for (int mk = 32; mk >= 1; mk >>= 1) {
    for (int e = 0; e < 4; e++) {
      ai[e] += __shfl_xor(ai[e], mk);
      af[e] += __shfl_xor(af[e], mk);
    }
  }
  if (lane == 0) {
    for (int e = 0; e < 4; e++) {
      ig[(long)row*NHEAD + e] = ai[e] + bi[e];
      fg[(long)row*NHEAD + e] = af[e] + bf_[e];
    }
  }
}

// ---- kernel 4: per-(b,h) scan ----
__global__ void scan_kernel(const float* __restrict__ ig, const float* __restrict__ fg,
                            float* __restrict__ a_out, float* __restrict__ m_out,
                            float* __restrict__ nf_out) {
  int bh = blockIdx.x, b = bh >> 2, h = bh & 3;
  int t = threadIdx.x;
  __shared__ float tot[256];
  long gbase = (long)b * S_LEN;
  float ls[8];
  float run = 0.f;
  for (int e = 0; e < 8; e++) {
    int s = t*8 + e;
    float x = fg[(gbase + s)*NHEAD + h];
    float l = fminf(x, 0.f) - log1pf(expf(-fabsf(x)));  // stable log_sigmoid
    run += l; ls[e] = run;
  }
  tot[t] = run;
  __syncthreads();
  if (t == 0) { float acc = 0.f; for (int i = 0; i < 256; i++) { float tmp = tot[i]; tot[i] = acc; acc += tmp; } }
  __syncthreads();
  float offc = tot[t];
  float av[8], am[8], csv[8];
  float runm = -1e30f;
  for (int e = 0; e < 8; e++) {
    int s = t*8 + e;
    float cs = ls[e] + offc;
    csv[e] = cs;
    float a = ig[(gbase + s)*NHEAD + h] - cs;
    av[e] = a;
    runm = fmaxf(runm, a);
    am[e] = runm;
  }
  __syncthreads();
  tot[t] = runm;
  __syncthreads();
  if (t == 0) { float acc = -1e30f; for (int i = 0; i < 256; i++) { float tmp = tot[i]; tot[i] = acc; acc = fmaxf(acc, tmp); } }
  __syncthreads();
  float offm = tot[t];
  long obase = (long)bh * S_LEN;
  for (int e = 0; e < 8; e++) {
    int s = t*8 + e;
    float mm = fmaxf(am[e], offm);
    a_out[obase + s]  = av[e];
    m_out[obase + s]  = mm;
    nf_out[obase + s] = expf(-(csv[e] + mm));
  }
}

// ---- kernel 5: partial flash blocks over (bh, 64-row i-tile, 256-key chunk) ----
// grid = 8 heads * 144 chunks = 1152 blocks; 4 waves/block, wave owns 16 rows.
// Accumulates unnormalized O into d_out (out layout) + rowsums via f32 atomics.
__global__ __launch_bounds__(256) void mlstm_partial_kernel(
    const short* __restrict__ Qb, const short* __restrict__ Kb, const short* __restrict__ VTb,
    const float* __restrict__ a_arr, const float* __restrict__ m_arr,
    float* __restrict__ outp, float* __restrict__ rsacc) {
  __shared__ short plds[4][16*36];
  const int w = threadIdx.x >> 6, lane = threadIdx.x & 63;
  const int lr = lane & 15, g = lane >> 4;

  // decode work item: bh, i-tile (64 rows), j-chunk (256 keys, causal-trimmed)
  const int bh = blockIdx.x / 144;
  int rem = blockIdx.x % 144;
  int it = 0;
  while (rem >= (it/4 + 1)) { rem -= it/4 + 1; ++it; }
  const int jc = rem;
  const int b = bh >> 2, h = bh & 3;
  const int i0 = it*64 + w*16;
  const long hq = (long)bh * S_LEN * DHD;
  const long arow = (long)bh * S_LEN;
  const f32x4 zz = {0.f,0.f,0.f,0.f};

  // preload Q fragments for this wave's 16 rows (whole DH=256)
  bf16x8 qf[8];
  const short* qptr = Qb + hq + (long)(i0 + lr) * DHD + g*8;
#pragma unroll
  for (int c = 0; c < 8; c++) qf[c] = *(const bf16x8*)(qptr + c*32);

  float mrow[4];
#pragma unroll
  for (int r = 0; r < 4; r++) mrow[r] = m_arr[arow + i0 + g*4 + r];

  f32x4 oacc[16];
#pragma unroll
  for (int t = 0; t < 16; t++) oacc[t] = zz;
  float rs[4] = {0.f,0.f,0.f,0.f};

  short* myp = plds[w];
  const int jstart = jc * 256;
  const int jend = min(jstart + 256, i0 + 16);   // causal trim per wave
  const int ntl = (jend - jstart + 31) >> 5;
  const short* kbase = Kb + hq + (long)lr * DHD + g*8;
  const short* vbase = VTb + hq + (long)lr * S_LEN + g*8;

  for (int jt = 0; jt < ntl; jt++) {
    const int j0 = jstart + jt * 32;
    f32x4 s0 = zz, s1 = zz;
    const short* kp = kbase + (long)j0 * DHD;
#pragma unroll
    for (int c = 0; c < 8; c++) {
      bf16x8 k0 = *(const bf16x8*)(kp + c*32);
      bf16x8 k1 = *(const bf16x8*)(kp + 16*DHD + c*32);
      s0 = __builtin_amdgcn_mfma_f32_16x16x32_bf16(qf[c], k0, s0, 0, 0, 0);
      s1 = __builtin_amdgcn_mfma_f32_16x16x32_bf16(qf[c], k1, s1, 0, 0, 0);
    }
    const float a0 = a_arr[arow + j0 + lr];
    const float a1 = a_arr[arow + j0 + 16 + lr];
    const bool needmask = (j0 + 31 > i0);
#pragma unroll
    for (int r = 0; r < 4; r++) {
      const int i = i0 + g*4 + r;
      float p0 = s0[r] * 0.0625f * __expf(a0 - mrow[r]);
      float p1 = s1[r] * 0.0625f * __expf(a1 - mrow[r]);
      if (needmask) {               // causal mask on diagonal tiles
        if (j0 + lr > i)      p0 = 0.f;
        if (j0 + 16 + lr > i) p1 = 0.f;
      }
      rs[r] += p0 + p1;
      myp[(g*4 + r)*36 + lr]      = f2b(p0);
      myp[(g*4 + r)*36 + 16 + lr] = f2b(p1);
    }
    // re-fragment P (C-layout) -> A-layout via per-wave LDS (no barrier needed)
    const short* rp = myp + lr*36 + g*8;
    short4v plo = *(const short4v*)rp;
    short4v phi = *(const short4v*)(rp + 4);
    bf16x8 pa = {plo[0],plo[1],plo[2],plo[3],phi[0],phi[1],phi[2],phi[3]};
    const short* vp = vbase + j0;
#pragma unroll
    for (int t = 0; t < 16; t++) {
      bf16x8 vf = *(const bf16x8*)(vp + (long)t * 16 * S_LEN);
      oacc[t] = __builtin_amdgcn_mfma_f32_16x16x32_bf16(pa, vf, oacc[t], 0, 0, 0);
    }
  }

  // atomic-accumulate partial O into d_out (final layout)
#pragma unroll
  for (int r = 0; r < 4; r++) {
    const int i = i0 + g*4 + r;
    float* orow = outp + ((long)(b*S_LEN + i))*HID + h*DHD + lr;
#pragma unroll
    for (int t = 0; t < 16; t++)
      unsafeAtomicAdd(orow + t*16, oacc[t][r]);
  }
  // rowsum: reduce across the 16 lanes sharing each row, one atomic per row
#pragma unroll
  for (int r = 0; r < 4; r++)
    for (int mk = 1; mk < 16; mk <<= 1)
      rs[r] += __shfl_xor(rs[r], mk);
  if (lr == 0) {
#pragma unroll
    for (int r = 0; r < 4; r++)
      unsafeAtomicAdd(&rsacc[arow + i0 + g*4 + r], rs[r]);
  }
}

// ---- kernel 6: finalize — normalizer + per-head LayerNorm, in place on d_out ----
// grid = B*S blocks; 4 waves/block, wave = one head; 4 f32 per lane.
__global__ __launch_bounds__(256) void finalize_kernel(
    float* __restrict__ outp, const float* __restrict__ rsacc,
    const float* __restrict__ nf_arr, const float* __restrict__ lns) {
  const int bi = blockIdx.x;                  // b*S + i
  const int h = threadIdx.x >> 6, lane = threadIdx.x & 63;
  const int b = bi >> 11, i = bi & (S_LEN-1);
  const int bh = b*NHEAD + h;
  const long roff = (long)bi * HID + (long)h*DHD;
  f32x4 xv = *(const f32x4*)(outp + roff + lane*4);
  const float rsv = rsacc[(long)bh*S_LEN + i];
  const float nfv = nf_arr[(long)bh*S_LEN + i];
  const float inv = 1.f / (fmaxf(fabsf(rsv), nfv) + 1e-6f);
  xv[0]*=inv; xv[1]*=inv; xv[2]*=inv; xv[3]*=inv;
  float sum = xv[0]+xv[1]+xv[2]+xv[3];
  float sq  = xv[0]*xv[0]+xv[1]*xv[1]+xv[2]*xv[2]+xv[3]*xv[3];
  for (int mk = 1; mk < 64; mk <<= 1) {
    sum += __shfl_xor(sum, mk);
    sq  += __shfl_xor(sq,  mk);
  }
  const float mean = sum * (1.f/256.f);
  const float var  = sq * (1.f/256.f) - mean*mean;
  const float rstd = rsqrtf(var + 1e-5f);
  f32x4 sc = *(const f32x4*)(lns + h*DHD + lane*4);
  f32x4 o;
  o[0]=(xv[0]-mean)*rstd*sc[0]; o[1]=(xv[1]-mean)*rstd*sc[1];
  o[2]=(xv[2]-mean)*rstd*sc[2]; o[3]=(xv[3]-mean)*rstd*sc[3];
  *(f32x4*)(outp + roff + lane*4) = o;
}

extern "C" void kernel_launch(void* const* d_in, const int* in_sizes, int n_in,
                              void* d_out, int out_size, void* d_ws, size_t ws_size,
                              hipStream_t stream) {
  const float* q   = (const float*)d_in[0];
  const float* k   = (const float*)d_in[1];
  const float* v   = (const float*)d_in[2];
  const float* wi  = (const float*)d_in[3];
  const float* bi  = (const float*)d_in[4];
  const float* wf  = (const float*)d_in[5];
  const float* bf_ = (const float*)d_in[6];
  const float* lns = (const float*)d_in[7];
  float* outp = (float*)d_out;

  // workspace layout (~25.6 MB): Qb, Kb, VTb bf16 + gate/scan arrays + rowsums
  char* ws = (char*)d_ws;
  const long nelem = (long)BH_CNT * S_LEN * DHD;      // 4,194,304
  short* Qb  = (short*)ws;
  short* Kb  = Qb + nelem;
  short* VTb = Kb + nelem;
  float* igA = (float*)(ws + 3*nelem*sizeof(short));
  float* fgA = igA + (long)BATCH*S_LEN*NHEAD;
  float* aA  = fgA + (long)BATCH*S_LEN*NHEAD;
  float* mA  = aA + (long)BH_CNT*S_LEN;
  float* nfA = mA + (long)BH_CNT*S_LEN;
  float* rsA = nfA + (long)BH_CNT*S_LEN;

  hipMemsetAsync(outp, 0, (size_t)out_size * sizeof(float), stream);
  hipMemsetAsync(rsA, 0, (size_t)BH_CNT * S_LEN * sizeof(float), stream);

  cast_heads_kernel<<<2048, 256, 0, stream>>>(q, Qb);
  cast_heads_kernel<<<2048, 256, 0, stream>>>(k, Kb);
  transpose_v_kernel<<<dim3(DHD/32, S_LEN/32, BH_CNT), 256, 0, stream>>>(v, VTb);
  gate_kernel<<<(BATCH*S_LEN)/4, 256, 0, stream>>>(q, k, v, wi, bi, wf, bf_, igA, fgA);
  scan_kernel<<<BH_CNT, 256, 0, stream>>>(igA, fgA, aA, mA, nfA);
  mlstm_partial_kernel<<<BH_CNT*144, 256, 0, stream>>>(Qb, Kb, VTb, aA, mA, outp, rsA);
  finalize_kernel<<<BATCH*S_LEN, 256, 0, stream>>>(outp, rsA, nfA, lns);
}

// Round 3
// 225.985 us; speedup vs baseline: 1.8130x; 1.1026x over previous
//
#include <hip/hip_runtime.h>
#include <hip/hip_bf16.h>

// mLSTM parallel-stabilized cell, MI355X (gfx950).
// B=2, S=2048, H=1024, NH=4, DH=256.
// Identity: max_log_D[i] = cs[i] + m[i], m[i] = prefixmax(ig[j]-cs[j]);
// D[i][j] = exp(a[j]-m[i]), a[j] = ig[j]-cs[j]. m is GLOBAL (precomputed), so
// partial O / rowsum over disjoint key chunks are additive -> j-split blocks
// with fp32 atomic accumulation into d_out, then a finalize pass.
// R3: LDS-staged K/V via global_load_lds (swizzled K tiles), uniform 128-key
// chunks, head->XCD affinity, 3 blocks/CU.

#define S_LEN 2048
#define DHD   256
#define NHEAD 4
#define BATCH 2
#define HID   1024
#define BH_CNT (BATCH*NHEAD)

typedef __attribute__((ext_vector_type(8))) short bf16x8;
typedef __attribute__((ext_vector_type(4))) short short4v;
typedef __attribute__((ext_vector_type(4))) float f32x4;

static __device__ __forceinline__ short f2b(float f) {
  __hip_bfloat16 h = __float2bfloat16(f);
  return *reinterpret_cast<short*>(&h);
}

// async global->LDS DMA, 16B per lane. LDS dest must be wave-uniform;
// HW writes lane l's data at dst + l*16.
static __device__ __forceinline__ void gload16(const void* src, void* ldsdst) {
  __builtin_amdgcn_global_load_lds(
      (const __attribute__((address_space(1))) void*)src,
      (__attribute__((address_space(3))) void*)ldsdst, 16, 0, 0);
}

// ---- kernel 1: cast q -> Qb (linear per-head) and k -> Kg (swizzled tiles) ----
// Kg layout: [bh][jt=64][32x256 tile, 16KB], within tile element (r,d) at
// short-offset r*256 + (d ^ ((r&7)<<3)).
__global__ void cast_qk_kernel(const float* __restrict__ q, const float* __restrict__ k,
                               short* __restrict__ Qb, short* __restrict__ Kg) {
  const int isk = (blockIdx.x >= 2048);
  long lin = ((long)(blockIdx.x & 2047) * blockDim.x + threadIdx.x) * 8;
  int d = (int)(lin % DHD);
  long r = lin / DHD;
  int s  = (int)(r % S_LEN);
  int bh = (int)(r / S_LEN);
  int b = bh >> 2, h = bh & 3;
  const float* src = (isk ? k : q) + ((long)(b*S_LEN + s))*HID + h*DHD + d;
  f32x4 v0 = *(const f32x4*)(src);
  f32x4 v1 = *(const f32x4*)(src + 4);
  bf16x8 o;
  o[0]=f2b(v0[0]); o[1]=f2b(v0[1]); o[2]=f2b(v0[2]); o[3]=f2b(v0[3]);
  o[4]=f2b(v1[0]); o[5]=f2b(v1[1]); o[6]=f2b(v1[2]); o[7]=f2b(v1[3]);
  if (!isk) {
    *(bf16x8*)(Qb + lin) = o;
  } else {
    int jt = s >> 5, rr = s & 31;
    long off = ((long)bh*64 + jt)*8192 + rr*256 + (d ^ ((rr & 7) << 3));
    *(bf16x8*)(Kg + off) = o;
  }
}

// ---- kernel 2: v (B,S,H) fp32 -> VT bf16 [(b,h), DH, S] (LDS-tiled transpose) ----
__global__ void transpose_v_kernel(const float* __restrict__ v, short* __restrict__ vt) {
  __shared__ short tile[32][33];
  int d0 = blockIdx.x * 32, j0 = blockIdx.y * 32, bh = blockIdx.z;
  int b = bh >> 2, h = bh & 3;
  int c = threadIdx.x & 31, rr = threadIdx.x >> 5;
  for (int kk = 0; kk < 32; kk += 8)
    tile[rr + kk][c] = f2b(v[((long)(b*S_LEN + j0 + rr + kk))*HID + h*DHD + d0 + c]);
  __syncthreads();
  for (int kk = 0; kk < 32; kk += 8)
    vt[((long)bh*DHD + d0 + rr + kk)*S_LEN + j0 + c] = tile[c][rr + kk];
}

// ---- kernel 3: gate projections (one wave per row; wi staged in LDS) ----
__global__ __launch_bounds__(256) void gate_kernel(
    const float* __restrict__ q, const float* __restrict__ k,
    const float* __restrict__ v,
    const float* __restrict__ wi, const float* __restrict__ bi,
    const float* __restrict__ wf, const float* __restrict__ bf_,
    float* __restrict__ ig, float* __restrict__ fg) {
  __shared__ float wls[3*HID*4];
  for (int i = threadIdx.x; i < 3*HID; i += 256)
    *(f32x4*)&wls[i*4] = *(const f32x4*)(wi + (long)i*4);
  __syncthreads();
  int row = blockIdx.x * 4 + (threadIdx.x >> 6);   // b*S + s
  int lane = threadIdx.x & 63;
  f32x4 ai = {0.f,0.f,0.f,0.f}, af = {0.f,0.f,0.f,0.f};
  long rbase = (long)row * HID;
  for (int c = lane; c < 3*HID; c += 64) {
    int p = c >> 10, idx = c & (HID-1);
    float x = (p == 0 ? q[rbase + idx] : (p == 1 ? k[rbase + idx] : v[rbase + idx]));
    f32x4 w4i = *(const f32x4*)&wls[c*4];
    f32x4 w4f = *(const f32x4*)(wf + (long)c*NHEAD);
    ai += x * w4i;
    af += x * w4f;
  }
  for (int mk = 32; mk >= 1; mk >>= 1) {
    for (int e = 0; e < 4; e++) {
      ai[e] += __shfl_xor(ai[e], mk);
      af[e] += __shfl_xor(af[e], mk);
    }
  }
  if (lane == 0) {
    for (int e = 0; e < 4; e++) {
      ig[(long)row*NHEAD + e] = ai[e] + bi[e];
      fg[(long)row*NHEAD + e] = af[e] + bf_[e];
    }
  }
}

// ---- kernel 4: per-(b,h) scan ----
__global__ void scan_kernel(const float* __restrict__ ig, const float* __restrict__ fg,
                            float* __restrict__ a_out, float* __restrict__ m_out,
                            float* __restrict__ nf_out) {
  int bh = blockIdx.x, b = bh >> 2, h = bh & 3;
  int t = threadIdx.x;
  __shared__ float tot[256];
  long gbase = (long)b * S_LEN;
  float ls[8];
  float run = 0.f;
  for (int e = 0; e < 8; e++) {
    int s = t*8 + e;
    float x = fg[(gbase + s)*NHEAD + h];
    float l = fminf(x, 0.f) - log1pf(expf(-fabsf(x)));  // stable log_sigmoid
    run += l; ls[e] = run;
  }
  tot[t] = run;
  __syncthreads();
  if (t == 0) { float acc = 0.f; for (int i = 0; i < 256; i++) { float tmp = tot[i]; tot[i] = acc; acc += tmp; } }
  __syncthreads();
  float offc = tot[t];
  float av[8], am[8], csv[8];
  float runm = -1e30f;
  for (int e = 0; e < 8; e++) {
    int s = t*8 + e;
    float cs = ls[e] + offc;
    csv[e] = cs;
    float a = ig[(gbase + s)*NHEAD + h] - cs;
    av[e] = a;
    runm = fmaxf(runm, a);
    am[e] = runm;
  }
  __syncthreads();
  tot[t] = runm;
  __syncthreads();
  if (t == 0) { float acc = -1e30f; for (int i = 0; i < 256; i++) { float tmp = tot[i]; tot[i] = acc; acc = fmaxf(acc, tmp); } }
  __syncthreads();
  float offm = tot[t];
  long obase = (long)bh * S_LEN;
  for (int e = 0; e < 8; e++) {
    int s = t*8 + e;
    float mm = fmaxf(am[e], offm);
    a_out[obase + s]  = av[e];
    m_out[obase + s]  = mm;
    nf_out[obase + s] = expf(-(csv[e] + mm));
  }
}

// ---- kernel 5: partial flash blocks, LDS-staged K/V ----
// grid = 8 bh * 272 chunks = 2176 blocks; bh = blockIdx.x & 7 (XCD affinity).
// chunk c -> (it, jc): i-tile it (64 rows), key chunk jc (128 keys).
// 4 waves/block, wave owns 16 rows; K/V tiles staged in LDS per 32-key tile.
__global__ __launch_bounds__(256, 3) void mlstm_partial_kernel(
    const short* __restrict__ Qb, const short* __restrict__ Kg, const short* __restrict__ VTg,
    const float* __restrict__ a_arr, const float* __restrict__ m_arr,
    float* __restrict__ outp, float* __restrict__ rsacc) {
  __shared__ alignas(16) short Kls[8192];   // 32 keys x 256 d, swizzled
  __shared__ alignas(16) short Vls[8192];   // 256 d x 32 keys, linear
  __shared__ alignas(16) short plds[4][16*36];
  const int w = threadIdx.x >> 6, lane = threadIdx.x & 63;
  const int lr = lane & 15, g = lane >> 4;

  const int bh = blockIdx.x & 7;
  int c = blockIdx.x >> 3;
  int it = 0;
  while (c >= ((it + 2) >> 1)) { c -= (it + 2) >> 1; ++it; }
  const int jc = c;
  const int b = bh >> 2, h = bh & 3;
  const int i0 = it*64 + w*16;
  const long hq = (long)bh * S_LEN * DHD;
  const long arow = (long)bh * S_LEN;
  const f32x4 zz = {0.f,0.f,0.f,0.f};

  // tiles staged by the block / computed by this wave
  const int ntb = min(4, (it*64 + 64 - jc*128 + 31) >> 5);
  const int ntw = max(0, min(4, (i0 + 16 - jc*128 + 31) >> 5));

  // preload Q fragments for this wave's 16 rows (whole DH=256)
  bf16x8 qf[8];
  const short* qptr = Qb + hq + (long)(i0 + lr) * DHD + g*8;
#pragma unroll
  for (int c8 = 0; c8 < 8; c8++) qf[c8] = *(const bf16x8*)(qptr + c8*32);

  float mrow[4];
#pragma unroll
  for (int r = 0; r < 4; r++) mrow[r] = m_arr[arow + i0 + g*4 + r];

  f32x4 oacc[16];
#pragma unroll
  for (int t = 0; t < 16; t++) oacc[t] = zz;
  float rs[4] = {0.f,0.f,0.f,0.f};

  short* myp = plds[w];
  const int sw = (lr & 7) << 3;

  for (int jt = 0; jt < ntb; jt++) {
    const int j0 = jc*128 + jt*32;
    // ---- stage K (16KB, swizzled-linear copy) + V (16KB) ----
    {
      const short* kgt = Kg + ((long)bh*64 + (j0 >> 5))*8192;
#pragma unroll
      for (int u = 0; u < 4; u++) {
        const int off = w*512 + u*2048;           // wave-uniform
        gload16(kgt + off + lane*8, &Kls[off]);
      }
#pragma unroll
      for (int u = 0; u < 4; u++) {
        const int off = w*512 + u*2048;           // wave-uniform
        const int o = off + lane*8;
        const int d = o >> 5, jo = o & 31;
        gload16(VTg + ((long)bh*DHD + d)*S_LEN + j0 + jo, &Vls[off]);
      }
    }
    __syncthreads();   // drains vmcnt -> LDS tiles ready

    if (jt < ntw) {
      f32x4 s0 = zz, s1 = zz;
#pragma unroll
      for (int c8 = 0; c8 < 8; c8++) {
        const int ko = lr*256 + ((c8*32 + g*8) ^ sw);
        bf16x8 k0 = *(const bf16x8*)&Kls[ko];
        bf16x8 k1 = *(const bf16x8*)&Kls[ko + 4096];
        s0 = __builtin_amdgcn_mfma_f32_16x16x32_bf16(qf[c8], k0, s0, 0, 0, 0);
        s1 = __builtin_amdgcn_mfma_f32_16x16x32_bf16(qf[c8], k1, s1, 0, 0, 0);
      }
      const float a0 = a_arr[arow + j0 + lr];
      const float a1 = a_arr[arow + j0 + 16 + lr];
      const bool needmask = (j0 + 31 > i0);
#pragma unroll
      for (int r = 0; r < 4; r++) {
        const int i = i0 + g*4 + r;
        float p0 = s0[r] * 0.0625f * __expf(a0 - mrow[r]);
        float p1 = s1[r] * 0.0625f * __expf(a1 - mrow[r]);
        if (needmask) {               // causal mask on diagonal tiles
          if (j0 + lr > i)      p0 = 0.f;
          if (j0 + 16 + lr > i) p1 = 0.f;
        }
        rs[r] += p0 + p1;
        myp[(g*4 + r)*36 + lr]      = f2b(p0);
        myp[(g*4 + r)*36 + 16 + lr] = f2b(p1);
      }
      // re-fragment P (C-layout) -> A-layout via per-wave LDS
      const short* rp = myp + lr*36 + g*8;
      short4v plo = *(const short4v*)rp;
      short4v phi = *(const short4v*)(rp + 4);
      bf16x8 pa = {plo[0],plo[1],plo[2],plo[3],phi[0],phi[1],phi[2],phi[3]};
#pragma unroll
      for (int t = 0; t < 16; t++) {
        bf16x8 vf = *(const bf16x8*)&Vls[(t*16 + lr)*32 + g*8];
        oacc[t] = __builtin_amdgcn_mfma_f32_16x16x32_bf16(pa, vf, oacc[t], 0, 0, 0);
      }
    }
    __syncthreads();   // all reads done before next stage overwrites
  }

  // atomic-accumulate partial O into d_out (final layout)
#pragma unroll
  for (int r = 0; r < 4; r++) {
    const int i = i0 + g*4 + r;
    float* orow = outp + ((long)(b*S_LEN + i))*HID + h*DHD + lr;
#pragma unroll
    for (int t = 0; t < 16; t++)
      unsafeAtomicAdd(orow + t*16, oacc[t][r]);
  }
  // rowsum: reduce across the 16 lanes sharing each row, one atomic per row
#pragma unroll
  for (int r = 0; r < 4; r++)
    for (int mk = 1; mk < 16; mk <<= 1)
      rs[r] += __shfl_xor(rs[r], mk);
  if (lr == 0) {
#pragma unroll
    for (int r = 0; r < 4; r++)
      unsafeAtomicAdd(&rsacc[arow + i0 + g*4 + r], rs[r]);
  }
}

// ---- kernel 6: finalize — normalizer + per-head LayerNorm, in place on d_out ----
__global__ __launch_bounds__(256) void finalize_kernel(
    float* __restrict__ outp, const float* __restrict__ rsacc,
    const float* __restrict__ nf_arr, const float* __restrict__ lns) {
  const int bi = blockIdx.x;                  // b*S + i
  const int h = threadIdx.x >> 6, lane = threadIdx.x & 63;
  const int b = bi >> 11, i = bi & (S_LEN-1);
  const int bh = b*NHEAD + h;
  const long roff = (long)bi * HID + (long)h*DHD;
  f32x4 xv = *(const f32x4*)(outp + roff + lane*4);
  const float rsv = rsacc[(long)bh*S_LEN + i];
  const float nfv = nf_arr[(long)bh*S_LEN + i];
  const float inv = 1.f / (fmaxf(fabsf(rsv), nfv) + 1e-6f);
  xv[0]*=inv; xv[1]*=inv; xv[2]*=inv; xv[3]*=inv;
  float sum = xv[0]+xv[1]+xv[2]+xv[3];
  float sq  = xv[0]*xv[0]+xv[1]*xv[1]+xv[2]*xv[2]+xv[3]*xv[3];
  for (int mk = 1; mk < 64; mk <<= 1) {
    sum += __shfl_xor(sum, mk);
    sq  += __shfl_xor(sq,  mk);
  }
  const float mean = sum * (1.f/256.f);
  const float var  = sq * (1.f/256.f) - mean*mean;
  const float rstd = rsqrtf(var + 1e-5f);
  f32x4 sc = *(const f32x4*)(lns + h*DHD + lane*4);
  f32x4 o;
  o[0]=(xv[0]-mean)*rstd*sc[0]; o[1]=(xv[1]-mean)*rstd*sc[1];
  o[2]=(xv[2]-mean)*rstd*sc[2]; o[3]=(xv[3]-mean)*rstd*sc[3];
  *(f32x4*)(outp + roff + lane*4) = o;
}

extern "C" void kernel_launch(void* const* d_in, const int* in_sizes, int n_in,
                              void* d_out, int out_size, void* d_ws, size_t ws_size,
                              hipStream_t stream) {
  const float* q   = (const float*)d_in[0];
  const float* k   = (const float*)d_in[1];
  const float* v   = (const float*)d_in[2];
  const float* wi  = (const float*)d_in[3];
  const float* bi  = (const float*)d_in[4];
  const float* wf  = (const float*)d_in[5];
  const float* bf_ = (const float*)d_in[6];
  const float* lns = (const float*)d_in[7];
  float* outp = (float*)d_out;

  // workspace layout (~25.6 MB): Qb, Kg, VTb bf16 + gate/scan arrays + rowsums
  char* ws = (char*)d_ws;
  const long nelem = (long)BH_CNT * S_LEN * DHD;      // 4,194,304
  short* Qb  = (short*)ws;
  short* Kg  = Qb + nelem;
  short* VTb = Kg + nelem;
  float* igA = (float*)(ws + 3*nelem*sizeof(short));
  float* fgA = igA + (long)BATCH*S_LEN*NHEAD;
  float* aA  = fgA + (long)BATCH*S_LEN*NHEAD;
  float* mA  = aA + (long)BH_CNT*S_LEN;
  float* nfA = mA + (long)BH_CNT*S_LEN;
  float* rsA = nfA + (long)BH_CNT*S_LEN;

  hipMemsetAsync(outp, 0, (size_t)out_size * sizeof(float), stream);
  hipMemsetAsync(rsA, 0, (size_t)BH_CNT * S_LEN * sizeof(float), stream);

  cast_qk_kernel<<<4096, 256, 0, stream>>>(q, k, Qb, Kg);
  transpose_v_kernel<<<dim3(DHD/32, S_LEN/32, BH_CNT), 256, 0, stream>>>(v, VTb);
  gate_kernel<<<(BATCH*S_LEN)/4, 256, 0, stream>>>(q, k, v, wi, bi, wf, bf_, igA, fgA);
  scan_kernel<<<BH_CNT, 256, 0, stream>>>(igA, fgA, aA, mA, nfA);
  mlstm_partial_kernel<<<BH_CNT*272, 256, 0, stream>>>(Qb, Kg, VTb, aA, mA, outp, rsA);
  finalize_kernel<<<BATCH*S_LEN, 256, 0, stream>>>(outp, rsA, nfA, lns);
}

// Round 4
// 179.989 us; speedup vs baseline: 2.2763x; 1.2555x over previous
//
#include <hip/hip_runtime.h>
#include <hip/hip_bf16.h>

// mLSTM parallel-stabilized cell, MI355X (gfx950).
// B=2, S=2048, H=1024, NH=4, DH=256.
// Identity: max_log_D[i] = cs[i] + m[i], m[i] = prefixmax(ig[j]-cs[j]);
// D[i][j] = exp(a[j]-m[i]), a[j] = ig[j]-cs[j]. m is GLOBAL (precomputed), so
// partial O / rowsum over disjoint key chunks are additive -> j-split blocks
// with fp32 atomic accumulation into d_out, then a finalize pass.
// R4: double-buffered K/V staging w/ counted vmcnt (T3/T4), V pre-swizzled in
// global (kills 8-way PV bank conflicts), 256-key chunks largest-first
// (halves atomic traffic), fused prep mega-kernel, parallel scan.

#define S_LEN 2048
#define DHD   256
#define NHEAD 4
#define BATCH 2
#define HID   1024
#define BH_CNT (BATCH*NHEAD)

typedef __attribute__((ext_vector_type(8))) short bf16x8;
typedef __attribute__((ext_vector_type(4))) short short4v;
typedef __attribute__((ext_vector_type(4))) float f32x4;

static __device__ __forceinline__ short f2b(float f) {
  __hip_bfloat16 h = __float2bfloat16(f);
  return *reinterpret_cast<short*>(&h);
}

// async global->LDS DMA, 16B per lane. LDS dest wave-uniform; lane l -> dst+l*16.
static __device__ __forceinline__ void gload16(const void* src, void* ldsdst) {
  __builtin_amdgcn_global_load_lds(
      (const __attribute__((address_space(1))) void*)src,
      (__attribute__((address_space(3))) void*)ldsdst, 16, 0, 0);
}

// ---- kernel 1 (fused prep): blocks [0,4096) cast q/k; [4096,8192) transpose v;
//      [8192,9216) gate projections. All independent -> full overlap in one launch.
// Kg layout: [bh][jt=64][32x256 tile]: (r,d) at r*256 + (d ^ ((r&7)<<3)).
// Vg layout: [bh][jt=64][256x32 tile]: (d,j) at d*32 + ((j&31) ^ (((d>>1)&3)<<3)).
__global__ __launch_bounds__(256) void prep_kernel(
    const float* __restrict__ q, const float* __restrict__ k, const float* __restrict__ v,
    const float* __restrict__ wi, const float* __restrict__ bi,
    const float* __restrict__ wf, const float* __restrict__ bf_,
    short* __restrict__ Qb, short* __restrict__ Kg, short* __restrict__ Vg,
    float* __restrict__ ig, float* __restrict__ fg) {
  __shared__ float wls[3*HID*4];          // gate branch (48 KB)
  __shared__ short tile[32][33];          // transpose branch
  const int bx = blockIdx.x;
  if (bx < 4096) {
    // ---- cast q -> Qb (linear), k -> Kg (swizzled tiles) ----
    const int isk = (bx >= 2048);
    long lin = ((long)(bx & 2047) * 256 + threadIdx.x) * 8;
    int d = (int)(lin % DHD);
    long r = lin / DHD;
    int s  = (int)(r % S_LEN);
    int bh = (int)(r / S_LEN);
    int b = bh >> 2, h = bh & 3;
    const float* src = (isk ? k : q) + ((long)(b*S_LEN + s))*HID + h*DHD + d;
    f32x4 v0 = *(const f32x4*)(src);
    f32x4 v1 = *(const f32x4*)(src + 4);
    bf16x8 o;
    o[0]=f2b(v0[0]); o[1]=f2b(v0[1]); o[2]=f2b(v0[2]); o[3]=f2b(v0[3]);
    o[4]=f2b(v1[0]); o[5]=f2b(v1[1]); o[6]=f2b(v1[2]); o[7]=f2b(v1[3]);
    if (!isk) {
      *(bf16x8*)(Qb + lin) = o;
    } else {
      int jt = s >> 5, rr = s & 31;
      long off = ((long)bh*64 + jt)*8192 + rr*256 + (d ^ ((rr & 7) << 3));
      *(bf16x8*)(Kg + off) = o;
    }
  } else if (bx < 8192) {
    // ---- transpose v -> Vg (swizzled tiles) ----
    const int t = bx - 4096;
    const int d0 = (t & 7) * 32, j0 = ((t >> 3) & 63) * 32, bh = t >> 9;
    const int b = bh >> 2, h = bh & 3;
    const int c = threadIdx.x & 31, rr = threadIdx.x >> 5;
    for (int kk = 0; kk < 32; kk += 8)
      tile[rr + kk][c] = f2b(v[((long)(b*S_LEN + j0 + rr + kk))*HID + h*DHD + d0 + c]);
    __syncthreads();
    const long base = ((long)bh*64 + (j0 >> 5)) * 8192;
    for (int kk = 0; kk < 32; kk += 8) {
      const int d = d0 + rr + kk;
      const int sw = ((d >> 1) & 3) << 3;
      Vg[base + (long)d*32 + (c ^ sw)] = tile[c][rr + kk];
    }
  } else {
    // ---- gate projections (one wave per row; wi staged in LDS) ----
    for (int i = threadIdx.x; i < 3*HID; i += 256)
      *(f32x4*)&wls[i*4] = *(const f32x4*)(wi + (long)i*4);
    __syncthreads();
    const int row = (bx - 8192) * 4 + (threadIdx.x >> 6);   // b*S + s
    const int lane = threadIdx.x & 63;
    f32x4 ai = {0.f,0.f,0.f,0.f}, af = {0.f,0.f,0.f,0.f};
    long rbase = (long)row * HID;
    for (int c = lane; c < 3*HID; c += 64) {
      int p = c >> 10, idx = c & (HID-1);
      float x = (p == 0 ? q[rbase + idx] : (p == 1 ? k[rbase + idx] : v[rbase + idx]));
      f32x4 w4i = *(const f32x4*)&wls[c*4];
      f32x4 w4f = *(const f32x4*)(wf + (long)c*NHEAD);
      ai += x * w4i;
      af += x * w4f;
    }
    for (int mk = 32; mk >= 1; mk >>= 1) {
      for (int e = 0; e < 4; e++) {
        ai[e] += __shfl_xor(ai[e], mk);
        af[e] += __shfl_xor(af[e], mk);
      }
    }
    if (lane == 0) {
      for (int e = 0; e < 4; e++) {
        ig[(long)row*NHEAD + e] = ai[e] + bi[e];
        fg[(long)row*NHEAD + e] = af[e] + bf_[e];
      }
    }
  }
}

// ---- kernel 2: per-(b,h) scan (parallel Hillis-Steele block scans) ----
__global__ void scan_kernel(const float* __restrict__ ig, const float* __restrict__ fg,
                            float* __restrict__ a_out, float* __restrict__ m_out,
                            float* __restrict__ nf_out) {
  int bh = blockIdx.x, b = bh >> 2, h = bh & 3;
  int t = threadIdx.x;
  __shared__ float tot[256];
  long gbase = (long)b * S_LEN;
  float ls[8];
  float run = 0.f;
  for (int e = 0; e < 8; e++) {
    int s = t*8 + e;
    float x = fg[(gbase + s)*NHEAD + h];
    float l = fminf(x, 0.f) - log1pf(expf(-fabsf(x)));  // stable log_sigmoid
    run += l; ls[e] = run;
  }
  tot[t] = run;
  __syncthreads();
  for (int off = 1; off < 256; off <<= 1) {
    float x = tot[t];
    if (t >= off) x += tot[t - off];
    __syncthreads();
    tot[t] = x;
    __syncthreads();
  }
  float offc = (t == 0) ? 0.f : tot[t-1];
  __syncthreads();
  float av[8], am[8], csv[8];
  float runm = -1e30f;
  for (int e = 0; e < 8; e++) {
    int s = t*8 + e;
    float cs = ls[e] + offc;
    csv[e] = cs;
    float a = ig[(gbase + s)*NHEAD + h] - cs;
    av[e] = a;
    runm = fmaxf(runm, a);
    am[e] = runm;
  }
  tot[t] = runm;
  __syncthreads();
  for (int off = 1; off < 256; off <<= 1) {
    float x = tot[t];
    if (t >= off) x = fmaxf(x, tot[t - off]);
    __syncthreads();
    tot[t] = x;
    __syncthreads();
  }
  float offm = (t == 0) ? -1e30f : tot[t-1];
  long obase = (long)bh * S_LEN;
  for (int e = 0; e < 8; e++) {
    int s = t*8 + e;
    float mm = fmaxf(am[e], offm);
    a_out[obase + s]  = av[e];
    m_out[obase + s]  = mm;
    nf_out[obase + s] = expf(-(csv[e] + mm));
  }
}

// ---- kernel 3: partial flash blocks, double-buffered LDS staging ----
// grid = 8 bh * 144 chunks; bh = blockIdx.x & 7 (XCD affinity).
// chunk -> (it, jc): i-tile it (64 rows), key chunk jc (256 keys), decoded
// LARGEST-FIRST (it descending) for tail packing.
__global__ __launch_bounds__(256, 2) void mlstm_partial_kernel(
    const short* __restrict__ Qb, const short* __restrict__ Kg, const short* __restrict__ Vg,
    const float* __restrict__ a_arr, const float* __restrict__ m_arr,
    float* __restrict__ outp, float* __restrict__ rsacc) {
  __shared__ alignas(16) short Kls[2][8192];   // 32 keys x 256 d, swizzled
  __shared__ alignas(16) short Vls[2][8192];   // 256 d x 32 keys, swizzled
  __shared__ alignas(16) short plds[4][16*36];
  const int w = threadIdx.x >> 6, lane = threadIdx.x & 63;
  const int lr = lane & 15, g = lane >> 4;

  const int bh = blockIdx.x & 7;
  int c = blockIdx.x >> 3;
  int it = 31;
  while (c >= ((it + 4) >> 2)) { c -= (it + 4) >> 2; --it; }
  const int jc = c;
  const int b = bh >> 2, h = bh & 3;
  const int i0 = it*64 + w*16;
  const long hq = (long)bh * S_LEN * DHD;
  const long arow = (long)bh * S_LEN;
  const f32x4 zz = {0.f,0.f,0.f,0.f};

  const int ntb = min(8, (((it+1)*64 - jc*256) >> 5));           // tiles staged
  const int ntw = min(8, max(1, (i0 + 16 - jc*256 + 31) >> 5));  // tiles computed

  // preload Q fragments (16 rows x DH=256), m, and the chunk's a[] values
  bf16x8 qf[8];
  const short* qptr = Qb + hq + (long)(i0 + lr) * DHD + g*8;
#pragma unroll
  for (int c8 = 0; c8 < 8; c8++) qf[c8] = *(const bf16x8*)(qptr + c8*32);

  float mrow[4];
#pragma unroll
  for (int r = 0; r < 4; r++) mrow[r] = m_arr[arow + i0 + g*4 + r];

  float ar[16];
#pragma unroll
  for (int jt = 0; jt < 8; jt++) {
    ar[2*jt]   = a_arr[arow + jc*256 + jt*32 + lr];
    ar[2*jt+1] = a_arr[arow + jc*256 + jt*32 + 16 + lr];
  }

  f32x4 oacc[16];
#pragma unroll
  for (int t = 0; t < 16; t++) oacc[t] = zz;
  float rs[4] = {0.f,0.f,0.f,0.f};

  short* myp = plds[w];
  const int sw = (lr & 7) << 3;

  auto STAGE = [&](int bsel, int jt) {
    const int gt = (jc*256 + jt*32) >> 5;          // global 32-key tile index
    const short* kgt = Kg + ((long)bh*64 + gt)*8192;
    const short* vgt = Vg + ((long)bh*64 + gt)*8192;
#pragma unroll
    for (int u = 0; u < 4; u++) {
      const int off = w*512 + u*2048;              // wave-uniform dst
      gload16(kgt + off + lane*8, &Kls[bsel][off]);
    }
#pragma unroll
    for (int u = 0; u < 4; u++) {
      const int off = w*512 + u*2048;
      gload16(vgt + off + lane*8, &Vls[bsel][off]);
    }
  };

  STAGE(0, 0);
  for (int jt = 0; jt < ntb; ++jt) {
    const int cb = jt & 1;
    if (jt + 1 < ntb) {
      STAGE(cb ^ 1, jt + 1);                       // prefetch next tile
      asm volatile("s_waitcnt vmcnt(8)" ::: "memory");   // tile jt staged
    } else {
      asm volatile("s_waitcnt vmcnt(0)" ::: "memory");
    }
    __builtin_amdgcn_s_barrier();

    if (jt < ntw) {
      const int j0 = jc*256 + jt*32;
      f32x4 s0 = zz, s1 = zz;
#pragma unroll
      for (int c8 = 0; c8 < 8; c8++) {
        const int ko = lr*256 + ((c8*32 + g*8) ^ sw);
        bf16x8 k0 = *(const bf16x8*)&Kls[cb][ko];
        bf16x8 k1 = *(const bf16x8*)&Kls[cb][ko + 4096];
        s0 = __builtin_amdgcn_mfma_f32_16x16x32_bf16(qf[c8], k0, s0, 0, 0, 0);
        s1 = __builtin_amdgcn_mfma_f32_16x16x32_bf16(qf[c8], k1, s1, 0, 0, 0);
      }
      const float a0 = ar[2*jt], a1 = ar[2*jt+1];
      const bool needmask = (j0 + 31 > i0);
#pragma unroll
      for (int r = 0; r < 4; r++) {
        const int i = i0 + g*4 + r;
        float p0 = s0[r] * 0.0625f * __expf(a0 - mrow[r]);
        float p1 = s1[r] * 0.0625f * __expf(a1 - mrow[r]);
        if (needmask) {               // causal mask on diagonal tiles
          if (j0 + lr > i)      p0 = 0.f;
          if (j0 + 16 + lr > i) p1 = 0.f;
        }
        rs[r] += p0 + p1;
        myp[(g*4 + r)*36 + lr]      = f2b(p0);
        myp[(g*4 + r)*36 + 16 + lr] = f2b(p1);
      }
      // re-fragment P (C-layout) -> A-layout via per-wave LDS
      const short* rp = myp + lr*36 + g*8;
      short4v plo = *(const short4v*)rp;
      short4v phi = *(const short4v*)(rp + 4);
      bf16x8 pa = {plo[0],plo[1],plo[2],plo[3],phi[0],phi[1],phi[2],phi[3]};
#pragma unroll
      for (int t = 0; t < 16; t++) {
        const int d = t*16 + lr;
        const int vo = d*32 + ((g*8) ^ (((d >> 1) & 3) << 3));
        bf16x8 vf = *(const bf16x8*)&Vls[cb][vo];
        oacc[t] = __builtin_amdgcn_mfma_f32_16x16x32_bf16(pa, vf, oacc[t], 0, 0, 0);
      }
    }
    __builtin_amdgcn_s_barrier();     // readers done before buffer reuse
  }

  // atomic-accumulate partial O into d_out (final layout)
#pragma unroll
  for (int r = 0; r < 4; r++) {
    const int i = i0 + g*4 + r;
    float* orow = outp + ((long)(b*S_LEN + i))*HID + h*DHD + lr;
#pragma unroll
    for (int t = 0; t < 16; t++)
      unsafeAtomicAdd(orow + t*16, oacc[t][r]);
  }
  // rowsum: reduce across the 16 lanes sharing each row, one atomic per row
#pragma unroll
  for (int r = 0; r < 4; r++)
    for (int mk = 1; mk < 16; mk <<= 1)
      rs[r] += __shfl_xor(rs[r], mk);
  if (lr == 0) {
#pragma unroll
    for (int r = 0; r < 4; r++)
      unsafeAtomicAdd(&rsacc[arow + i0 + g*4 + r], rs[r]);
  }
}

// ---- kernel 4: finalize — normalizer + per-head LayerNorm, in place on d_out ----
__global__ __launch_bounds__(256) void finalize_kernel(
    float* __restrict__ outp, const float* __restrict__ rsacc,
    const float* __restrict__ nf_arr, const float* __restrict__ lns) {
  const int bi = blockIdx.x;                  // b*S + i
  const int h = threadIdx.x >> 6, lane = threadIdx.x & 63;
  const int b = bi >> 11, i = bi & (S_LEN-1);
  const int bh = b*NHEAD + h;
  const long roff = (long)bi * HID + (long)h*DHD;
  f32x4 xv = *(const f32x4*)(outp + roff + lane*4);
  const float rsv = rsacc[(long)bh*S_LEN + i];
  const float nfv = nf_arr[(long)bh*S_LEN + i];
  const float inv = 1.f / (fmaxf(fabsf(rsv), nfv) + 1e-6f);
  xv[0]*=inv; xv[1]*=inv; xv[2]*=inv; xv[3]*=inv;
  float sum = xv[0]+xv[1]+xv[2]+xv[3];
  float sq  = xv[0]*xv[0]+xv[1]*xv[1]+xv[2]*xv[2]+xv[3]*xv[3];
  for (int mk = 1; mk < 64; mk <<= 1) {
    sum += __shfl_xor(sum, mk);
    sq  += __shfl_xor(sq,  mk);
  }
  const float mean = sum * (1.f/256.f);
  const float var  = sq * (1.f/256.f) - mean*mean;
  const float rstd = rsqrtf(var + 1e-5f);
  f32x4 sc = *(const f32x4*)(lns + h*DHD + lane*4);
  f32x4 o;
  o[0]=(xv[0]-mean)*rstd*sc[0]; o[1]=(xv[1]-mean)*rstd*sc[1];
  o[2]=(xv[2]-mean)*rstd*sc[2]; o[3]=(xv[3]-mean)*rstd*sc[3];
  *(f32x4*)(outp + roff + lane*4) = o;
}

extern "C" void kernel_launch(void* const* d_in, const int* in_sizes, int n_in,
                              void* d_out, int out_size, void* d_ws, size_t ws_size,
                              hipStream_t stream) {
  const float* q   = (const float*)d_in[0];
  const float* k   = (const float*)d_in[1];
  const float* v   = (const float*)d_in[2];
  const float* wi  = (const float*)d_in[3];
  const float* bi  = (const float*)d_in[4];
  const float* wf  = (const float*)d_in[5];
  const float* bf_ = (const float*)d_in[6];
  const float* lns = (const float*)d_in[7];
  float* outp = (float*)d_out;

  // workspace layout (~25.6 MB): Qb, Kg, Vg bf16 + gate/scan arrays + rowsums
  char* ws = (char*)d_ws;
  const long nelem = (long)BH_CNT * S_LEN * DHD;      // 4,194,304
  short* Qb  = (short*)ws;
  short* Kg  = Qb + nelem;
  short* Vg  = Kg + nelem;
  float* igA = (float*)(ws + 3*nelem*sizeof(short));
  float* fgA = igA + (long)BATCH*S_LEN*NHEAD;
  float* aA  = fgA + (long)BATCH*S_LEN*NHEAD;
  float* mA  = aA + (long)BH_CNT*S_LEN;
  float* nfA = mA + (long)BH_CNT*S_LEN;
  float* rsA = nfA + (long)BH_CNT*S_LEN;

  hipMemsetAsync(outp, 0, (size_t)out_size * sizeof(float), stream);
  hipMemsetAsync(rsA, 0, (size_t)BH_CNT * S_LEN * sizeof(float), stream);

  prep_kernel<<<9216, 256, 0, stream>>>(q, k, v, wi, bi, wf, bf_, Qb, Kg, Vg, igA, fgA);
  scan_kernel<<<BH_CNT, 256, 0, stream>>>(igA, fgA, aA, mA, nfA);
  mlstm_partial_kernel<<<BH_CNT*144, 256, 0, stream>>>(Qb, Kg, Vg, aA, mA, outp, rsA);
  finalize_kernel<<<BATCH*S_LEN, 256, 0, stream>>>(outp, rsA, nfA, lns);
}

// Round 5
// 165.081 us; speedup vs baseline: 2.4818x; 1.0903x over previous
//
#include <hip/hip_runtime.h>
#include <hip/hip_bf16.h>

// mLSTM parallel-stabilized cell, MI355X (gfx950).
// B=2, S=2048, H=1024, NH=4, DH=256.
// Identity: max_log_D[i] = cs[i] + m[i], m[i] = prefixmax(ig[j]-cs[j]);
// D[i][j] = exp(a[j]-m[i]), a[j] = ig[j]-cs[j], exponent always <= 0.
// R5: NO atomics. 256 blocks = (bh, 64-row tile), 1/CU. 4 waves =
// 2 row-halves (32 rows, frag reuse) x 2 key-parities; dbuf LDS staging w/
// counted vmcnt; in-LDS parity combine + LN epilogue. Fused single prep pass.

#define S_LEN 2048
#define DHD   256
#define NHEAD 4
#define BATCH 2
#define HID   1024
#define BH_CNT (BATCH*NHEAD)

typedef __attribute__((ext_vector_type(8))) short bf16x8;
typedef __attribute__((ext_vector_type(4))) short short4v;
typedef __attribute__((ext_vector_type(4))) float f32x4;

static __device__ __forceinline__ short f2b(float f) {
  __hip_bfloat16 h = __float2bfloat16(f);
  return *reinterpret_cast<short*>(&h);
}

// async global->LDS DMA, 16B/lane. ldsdst wave-uniform; lane l -> dst + l*16B.
static __device__ __forceinline__ void gload16(const void* src, void* ldsdst) {
  __builtin_amdgcn_global_load_lds(
      (const __attribute__((address_space(1))) void*)src,
      (__attribute__((address_space(3))) void*)ldsdst, 16, 0, 0);
}

// ---- kernel 1 (fused prep): 256 blocks x 512 thr, 32-row slabs.
// Per block: cast q->Qb, k->Kg(swizzled); transpose v->Vg(swizzled); gates.
// Kg tile [bh][jt][32x256]: (r,d) at r*256 + (d ^ ((r&7)<<3)).
// Vg tile [bh][jt][256x32]: (d,j) at d*32 + (j ^ (((d>>1)&3)<<3)).
__global__ __launch_bounds__(512) void prep_kernel(
    const float* __restrict__ q, const float* __restrict__ k, const float* __restrict__ v,
    const float* __restrict__ wi, const float* __restrict__ bi,
    const float* __restrict__ wf, const float* __restrict__ bf_,
    short* __restrict__ Qb, short* __restrict__ Kg, short* __restrict__ Vg,
    float* __restrict__ ig, float* __restrict__ fg) {
  __shared__ float wls[3*HID*4];          // 48 KB igate weights
  __shared__ float wfls[3*HID*4];         // 48 KB fgate weights
  __shared__ short vtile[8][32][33];      // per-wave transpose tiles
  const int tid = threadIdx.x;
  const int w = tid >> 6, lane = tid & 63;
  const int bs0 = blockIdx.x * 32;        // first (b*S+s) row of slab
  const int b = bs0 >> 11, s0 = bs0 & (S_LEN-1);
  const int jt = s0 >> 5;                 // slab == one 32-key tile index

  // stage both weight matrices (for the gate phase)
  for (int i = tid; i < 3*HID; i += 512) {
    *(f32x4*)&wls[i*4]  = *(const f32x4*)(wi + (long)i*4);
    *(f32x4*)&wfls[i*4] = *(const f32x4*)(wf + (long)i*4);
  }

  // ---- cast q,k (32 rows x 1024 each) ----
#pragma unroll
  for (int i = 0; i < 8; i++) {
    const int idx = i*4096 + tid*8;
    const int rl = idx >> 10, col = idx & 1023;
    const int s = s0 + rl, hh = col >> 8, d = col & 255;
    const long srcoff = ((long)(b*S_LEN + s))*HID + col;
    const int bh = b*NHEAD + hh;
    {
      f32x4 v0 = *(const f32x4*)(q + srcoff);
      f32x4 v1 = *(const f32x4*)(q + srcoff + 4);
      bf16x8 o;
      o[0]=f2b(v0[0]); o[1]=f2b(v0[1]); o[2]=f2b(v0[2]); o[3]=f2b(v0[3]);
      o[4]=f2b(v1[0]); o[5]=f2b(v1[1]); o[6]=f2b(v1[2]); o[7]=f2b(v1[3]);
      *(bf16x8*)(Qb + ((long)bh*S_LEN + s)*DHD + d) = o;
    }
    {
      f32x4 v0 = *(const f32x4*)(k + srcoff);
      f32x4 v1 = *(const f32x4*)(k + srcoff + 4);
      bf16x8 o;
      o[0]=f2b(v0[0]); o[1]=f2b(v0[1]); o[2]=f2b(v0[2]); o[3]=f2b(v0[3]);
      o[4]=f2b(v1[0]); o[5]=f2b(v1[1]); o[6]=f2b(v1[2]); o[7]=f2b(v1[3]);
      const int rr = s & 31;
      *(bf16x8*)(Kg + ((long)bh*64 + jt)*8192 + rr*256 + (d ^ ((rr & 7) << 3))) = o;
    }
  }

  // ---- transpose v into Vg (per-wave 32x32 tiles; 4 passes x 8 waves) ----
  {
    const int c = lane & 31, rh = lane >> 5;
    for (int pass = 0; pass < 4; pass++) {
      const int ti = pass*8 + w;          // 32 tiles = 4 heads x 8 d-blocks
      const int hh = ti >> 3, d0 = (ti & 7) * 32;
      const int bh = b*NHEAD + hh;
#pragma unroll
      for (int kk = 0; kk < 32; kk += 2)
        vtile[w][kk + rh][c] =
            f2b(v[((long)(b*S_LEN + s0 + kk + rh))*HID + hh*DHD + d0 + c]);
      const long base = ((long)bh*64 + jt) * 8192;
#pragma unroll
      for (int kk = 0; kk < 32; kk += 2) {
        const int d = d0 + kk + rh;
        Vg[base + (long)d*32 + (c ^ ((((d >> 1) & 3)) << 3))] = vtile[w][c][kk + rh];
      }
    }
  }

  __syncthreads();   // weights staged

  // ---- gates: 8 waves x 4 iters = 32 rows, one wave per row ----
  for (int itg = 0; itg < 4; itg++) {
    const int row = bs0 + itg*8 + w;
    f32x4 ai = {0.f,0.f,0.f,0.f}, af = {0.f,0.f,0.f,0.f};
    const long rbase = (long)row * HID;
    for (int c = lane; c < 3*HID; c += 64) {
      const int p = c >> 10, idx = c & (HID-1);
      const float x = (p == 0 ? q[rbase + idx] : (p == 1 ? k[rbase + idx] : v[rbase + idx]));
      ai += x * *(const f32x4*)&wls[c*4];
      af += x * *(const f32x4*)&wfls[c*4];
    }
    for (int mk = 32; mk >= 1; mk >>= 1) {
      for (int e = 0; e < 4; e++) {
        ai[e] += __shfl_xor(ai[e], mk);
        af[e] += __shfl_xor(af[e], mk);
      }
    }
    if (lane == 0) {
      for (int e = 0; e < 4; e++) {
        ig[(long)row*NHEAD + e] = ai[e] + bi[e];
        fg[(long)row*NHEAD + e] = af[e] + bf_[e];
      }
    }
  }
}

// ---- kernel 2: per-(b,h) scan (parallel Hillis-Steele) ----
__global__ void scan_kernel(const float* __restrict__ ig, const float* __restrict__ fg,
                            float* __restrict__ a_out, float* __restrict__ m_out,
                            float* __restrict__ nf_out) {
  int bh = blockIdx.x, b = bh >> 2, h = bh & 3;
  int t = threadIdx.x;
  __shared__ float tot[256];
  long gbase = (long)b * S_LEN;
  float ls[8];
  float run = 0.f;
  for (int e = 0; e < 8; e++) {
    int s = t*8 + e;
    float x = fg[(gbase + s)*NHEAD + h];
    float l = fminf(x, 0.f) - log1pf(expf(-fabsf(x)));  // stable log_sigmoid
    run += l; ls[e] = run;
  }
  tot[t] = run;
  __syncthreads();
  for (int off = 1; off < 256; off <<= 1) {
    float x = tot[t];
    if (t >= off) x += tot[t - off];
    __syncthreads();
    tot[t] = x;
    __syncthreads();
  }
  float offc = (t == 0) ? 0.f : tot[t-1];
  __syncthreads();
  float av[8], am[8], csv[8];
  float runm = -1e30f;
  for (int e = 0; e < 8; e++) {
    int s = t*8 + e;
    float cs = ls[e] + offc;
    csv[e] = cs;
    float a = ig[(gbase + s)*NHEAD + h] - cs;
    av[e] = a;
    runm = fmaxf(runm, a);
    am[e] = runm;
  }
  tot[t] = runm;
  __syncthreads();
  for (int off = 1; off < 256; off <<= 1) {
    float x = tot[t];
    if (t >= off) x = fmaxf(x, tot[t - off]);
    __syncthreads();
    tot[t] = x;
    __syncthreads();
  }
  float offm = (t == 0) ? -1e30f : tot[t-1];
  long obase = (long)bh * S_LEN;
  for (int e = 0; e < 8; e++) {
    int s = t*8 + e;
    float mm = fmaxf(am[e], offm);
    a_out[obase + s]  = av[e];
    m_out[obase + s]  = mm;
    nf_out[obase + s] = expf(-(csv[e] + mm));
  }
}

// ---- kernel 3: main. 256 blocks = (bh, it). 4 waves = 2 rg2 x 2 kp. ----
__global__ __launch_bounds__(256, 1) void mlstm_main_kernel(
    const short* __restrict__ Qb, const short* __restrict__ Kg, const short* __restrict__ Vg,
    const float* __restrict__ a_arr, const float* __restrict__ m_arr,
    const float* __restrict__ nf_arr, const float* __restrict__ lns,
    float* __restrict__ outp) {
  __shared__ alignas(16) short Kst[2][2][8192];   // [dbuf][parity][32k x 256d swz]
  __shared__ alignas(16) short Vst[2][2][8192];   // [dbuf][parity][256d x 32j swz]
  __shared__ alignas(16) short plds[4][16*36];
  const int w = threadIdx.x >> 6, lane = threadIdx.x & 63;
  const int lr = lane & 15, g = lane >> 4;
  const int rg2 = w >> 1, kp = w & 1;
  const int bh = blockIdx.x & 7, it = blockIdx.x >> 3;
  const int b = bh >> 2, h = bh & 3;
  const int R0 = it*64 + rg2*32;          // wave's first global row
  const long hq = (long)bh * S_LEN * DHD;
  const long arow = (long)bh * S_LEN;
  const int np = it + 1;                  // periods (2 tiles each)
  const int ntw = it*2 + rg2 + 1;         // wave computes jt < ntw (parity kp)
  const f32x4 zz = {0.f,0.f,0.f,0.f};
  const int sw = (lr & 7) << 3;

  // Q fragments for the wave's 32 rows (two 16-row MFMA groups)
  bf16x8 qfa[8], qfb[8];
  const short* qpa = Qb + hq + (long)(R0 + lr)*DHD + g*8;
#pragma unroll
  for (int c8 = 0; c8 < 8; c8++) {
    qfa[c8] = *(const bf16x8*)(qpa + c8*32);
    qfb[c8] = *(const bf16x8*)(qpa + 16*DHD + c8*32);
  }
  float ma[4], mb[4];
#pragma unroll
  for (int r = 0; r < 4; r++) {
    ma[r] = m_arr[arow + R0 + g*4 + r];
    mb[r] = m_arr[arow + R0 + 16 + g*4 + r];
  }

  f32x4 oa[16], ob[16];
#pragma unroll
  for (int t = 0; t < 16; t++) { oa[t] = zz; ob[t] = zz; }
  float rs_a[4] = {0,0,0,0}, rs_b[4] = {0,0,0,0};
  short* myp = plds[w];

  // wave w stages one 16KB tile-buffer per period: w<2 -> K parity w, else V.
  auto STAGE = [&](int pb, int p) {
    const int jts = 2*p + (w & 1);
    short* dst = (w < 2) ? &Kst[pb][w & 1][0] : &Vst[pb][w & 1][0];
    const short* src = ((w < 2) ? Kg : Vg) + ((long)bh*64 + jts)*8192 + lane*8;
#pragma unroll
    for (int u = 0; u < 16; u++)
      gload16(src + u*512, dst + u*512);
  };

  float aC0, aC1, aN0 = 0.f, aN1 = 0.f;
  STAGE(0, 0);
  { const int j0 = kp*32;
    aC0 = a_arr[arow + j0 + lr]; aC1 = a_arr[arow + j0 + 16 + lr]; }

  for (int p = 0; p < np; ++p) {
    const int pb = p & 1;
    if (p + 1 < np) {
      STAGE(pb ^ 1, p + 1);
      { const int j0 = (2*(p+1) + kp)*32;
        aN0 = a_arr[arow + j0 + lr]; aN1 = a_arr[arow + j0 + 16 + lr]; }
      asm volatile("s_waitcnt vmcnt(18)" ::: "memory");
    } else {
      asm volatile("s_waitcnt vmcnt(0)" ::: "memory");
    }
    __builtin_amdgcn_s_barrier();

    const int jtc = 2*p + kp;
    if (jtc < ntw) {
      const int j0 = jtc*32;
      const short* Kt = &Kst[pb][kp][0];
      const short* Vt = &Vst[pb][kp][0];
      f32x4 s0a = zz, s1a = zz, s0b = zz, s1b = zz;
#pragma unroll
      for (int c8 = 0; c8 < 8; c8++) {
        const int ko = lr*256 + ((c8*32 + g*8) ^ sw);
        bf16x8 k0 = *(const bf16x8*)&Kt[ko];
        bf16x8 k1 = *(const bf16x8*)&Kt[ko + 4096];
        s0a = __builtin_amdgcn_mfma_f32_16x16x32_bf16(qfa[c8], k0, s0a, 0, 0, 0);
        s0b = __builtin_amdgcn_mfma_f32_16x16x32_bf16(qfb[c8], k0, s0b, 0, 0, 0);
        s1a = __builtin_amdgcn_mfma_f32_16x16x32_bf16(qfa[c8], k1, s1a, 0, 0, 0);
        s1b = __builtin_amdgcn_mfma_f32_16x16x32_bf16(qfb[c8], k1, s1b, 0, 0, 0);
      }
      // ---- group a: P + re-fragment ----
      bf16x8 pa_a, pa_b;
      {
        const bool needmask = (j0 + 31 > R0);
#pragma unroll
        for (int r = 0; r < 4; r++) {
          const int i = R0 + g*4 + r;
          float p0 = s0a[r] * 0.0625f * __expf(aC0 - ma[r]);
          float p1 = s1a[r] * 0.0625f * __expf(aC1 - ma[r]);
          if (needmask) {
            if (j0 + lr > i)      p0 = 0.f;
            if (j0 + 16 + lr > i) p1 = 0.f;
          }
          rs_a[r] += p0 + p1;
          myp[(g*4 + r)*36 + lr]      = f2b(p0);
          myp[(g*4 + r)*36 + 16 + lr] = f2b(p1);
        }
        const short* rp = myp + lr*36 + g*8;
        short4v plo = *(const short4v*)rp;
        short4v phi = *(const short4v*)(rp + 4);
        pa_a = bf16x8{plo[0],plo[1],plo[2],plo[3],phi[0],phi[1],phi[2],phi[3]};
      }
      // ---- group b ----
      {
        const bool needmask = (j0 + 31 > R0 + 16);
#pragma unroll
        for (int r = 0; r < 4; r++) {
          const int i = R0 + 16 + g*4 + r;
          float p0 = s0b[r] * 0.0625f * __expf(aC0 - mb[r]);
          float p1 = s1b[r] * 0.0625f * __expf(aC1 - mb[r]);
          if (needmask) {
            if (j0 + lr > i)      p0 = 0.f;
            if (j0 + 16 + lr > i) p1 = 0.f;
          }
          rs_b[r] += p0 + p1;
          myp[(g*4 + r)*36 + lr]      = f2b(p0);
          myp[(g*4 + r)*36 + 16 + lr] = f2b(p1);
        }
        const short* rp = myp + lr*36 + g*8;
        short4v plo = *(const short4v*)rp;
        short4v phi = *(const short4v*)(rp + 4);
        pa_b = bf16x8{plo[0],plo[1],plo[2],plo[3],phi[0],phi[1],phi[2],phi[3]};
      }
      // ---- PV: read each V fragment ONCE, feed both row groups ----
#pragma unroll
      for (int t = 0; t < 16; t++) {
        const int d = t*16 + lr;
        const int vo = d*32 + ((g*8) ^ (((d >> 1) & 3) << 3));
        bf16x8 vf = *(const bf16x8*)&Vt[vo];
        oa[t] = __builtin_amdgcn_mfma_f32_16x16x32_bf16(pa_a, vf, oa[t], 0, 0, 0);
        ob[t] = __builtin_amdgcn_mfma_f32_16x16x32_bf16(pa_b, vf, ob[t], 0, 0, 0);
      }
    }
    __builtin_amdgcn_s_barrier();
    if (p + 1 < np) { aC0 = aN0; aC1 = aN1; }
  }

  // ---- rowsum reduce over the 16 key-columns ----
#pragma unroll
  for (int r = 0; r < 4; r++)
    for (int mk = 1; mk < 16; mk <<= 1) {
      rs_a[r] += __shfl_xor(rs_a[r], mk);
      rs_b[r] += __shfl_xor(rs_b[r], mk);
    }

  // ---- combine key-parities via LDS (kp=1 writes, kp=0 reduces + LN) ----
  float* Ols = (float*)&Kst[0][0][0];   // 64 rows x 256 d fp32 = 64 KB
  float* rsl = (float*)&Vst[0][0][0];   // 64 rowsums
  __syncthreads();
  if (kp == 1) {
#pragma unroll
    for (int r = 0; r < 4; r++) {
      const int rla = rg2*32 + g*4 + r, rlb = rla + 16;
#pragma unroll
      for (int t = 0; t < 16; t++) {
        Ols[(long)rla*256 + t*16 + lr] = oa[t][r];
        Ols[(long)rlb*256 + t*16 + lr] = ob[t][r];
      }
      if (lr == 0) { rsl[rla] = rs_a[r]; rsl[rlb] = rs_b[r]; }
    }
  }
  __syncthreads();
  if (kp == 0) {
    float sc[16];
#pragma unroll
    for (int t = 0; t < 16; t++) sc[t] = lns[h*DHD + t*16 + lr];
    for (int grp = 0; grp < 2; grp++) {
      f32x4* acc = grp ? ob : oa;
      float* rsv = grp ? rs_b : rs_a;
#pragma unroll
      for (int r = 0; r < 4; r++) {
        const int rl = rg2*32 + grp*16 + g*4 + r;
        const int i = R0 + grp*16 + g*4 + r;
        const float rst = rsv[r] + rsl[rl];
        const float nfv = nf_arr[arow + i];
        const float inv = 1.f / (fmaxf(fabsf(rst), nfv) + 1e-6f);
        float sum = 0.f, sq = 0.f;
        float xv[16];
#pragma unroll
        for (int t = 0; t < 16; t++) {
          float x = (acc[t][r] + Ols[(long)rl*256 + t*16 + lr]) * inv;
          xv[t] = x; sum += x; sq += x*x;
        }
        for (int mk = 1; mk < 16; mk <<= 1) {
          sum += __shfl_xor(sum, mk);
          sq  += __shfl_xor(sq,  mk);
        }
        const float mean = sum * (1.f/256.f);
        const float var  = sq * (1.f/256.f) - mean*mean;
        const float rstd = rsqrtf(var + 1e-5f);
        float* orow = outp + ((long)(b*S_LEN + i))*HID + h*DHD + lr;
#pragma unroll
        for (int t = 0; t < 16; t++)
          orow[t*16] = (xv[t] - mean) * rstd * sc[t];
      }
    }
  }
}

extern "C" void kernel_launch(void* const* d_in, const int* in_sizes, int n_in,
                              void* d_out, int out_size, void* d_ws, size_t ws_size,
                              hipStream_t stream) {
  const float* q   = (const float*)d_in[0];
  const float* k   = (const float*)d_in[1];
  const float* v   = (const float*)d_in[2];
  const float* wi  = (const float*)d_in[3];
  const float* bi  = (const float*)d_in[4];
  const float* wf  = (const float*)d_in[5];
  const float* bf_ = (const float*)d_in[6];
  const float* lns = (const float*)d_in[7];
  float* outp = (float*)d_out;

  char* ws = (char*)d_ws;
  const long nelem = (long)BH_CNT * S_LEN * DHD;      // 4,194,304
  short* Qb  = (short*)ws;
  short* Kg  = Qb + nelem;
  short* Vg  = Kg + nelem;
  float* igA = (float*)(ws + 3*nelem*sizeof(short));
  float* fgA = igA + (long)BATCH*S_LEN*NHEAD;
  float* aA  = fgA + (long)BATCH*S_LEN*NHEAD;
  float* mA  = aA + (long)BH_CNT*S_LEN;
  float* nfA = mA + (long)BH_CNT*S_LEN;

  prep_kernel<<<(BATCH*S_LEN)/32, 512, 0, stream>>>(q, k, v, wi, bi, wf, bf_,
                                                    Qb, Kg, Vg, igA, fgA);
  scan_kernel<<<BH_CNT, 256, 0, stream>>>(igA, fgA, aA, mA, nfA);
  mlstm_main_kernel<<<BH_CNT*32, 256, 0, stream>>>(Qb, Kg, Vg, aA, mA, nfA, lns, outp);
}

// Round 6
// 161.949 us; speedup vs baseline: 2.5298x; 1.0193x over previous
//
#include <hip/hip_runtime.h>
#include <hip/hip_bf16.h>

// mLSTM parallel-stabilized cell, MI355X (gfx950).
// B=2, S=2048, H=1024, NH=4, DH=256.
// Identity: max_log_D[i] = cs[i] + m[i], m[i] = prefixmax(ig[j]-cs[j]);
// D[i][j] = exp(a[j]-m[i]), a[j] = ig[j]-cs[j], exponent always <= 0.
// R6: prep rebuilt — no weight LDS (gate partials fused into streaming reads,
// register W-slices + shfl reduce + atomics), Qb eliminated (main casts Q
// inline from fp32). Main: correct vmcnt(16), setprio around MFMA.

#define S_LEN 2048
#define DHD   256
#define NHEAD 4
#define BATCH 2
#define HID   1024
#define BH_CNT (BATCH*NHEAD)

typedef __attribute__((ext_vector_type(8))) short bf16x8;
typedef __attribute__((ext_vector_type(4))) short short4v;
typedef __attribute__((ext_vector_type(4))) float f32x4;

static __device__ __forceinline__ short f2b(float f) {
  __hip_bfloat16 h = __float2bfloat16(f);
  return *reinterpret_cast<short*>(&h);
}

static __device__ __forceinline__ bf16x8 pack8(f32x4 a, f32x4 b) {
  bf16x8 o;
  o[0]=f2b(a[0]); o[1]=f2b(a[1]); o[2]=f2b(a[2]); o[3]=f2b(a[3]);
  o[4]=f2b(b[0]); o[5]=f2b(b[1]); o[6]=f2b(b[2]); o[7]=f2b(b[3]);
  return o;
}

// async global->LDS DMA, 16B/lane. ldsdst wave-uniform; lane l -> dst + l*16B.
static __device__ __forceinline__ void gload16(const void* src, void* ldsdst) {
  __builtin_amdgcn_global_load_lds(
      (const __attribute__((address_space(1))) void*)src,
      (__attribute__((address_space(3))) void*)ldsdst, 16, 0, 0);
}

// ---- kernel 1 (prep): grid 8192 x 256.
// bx <  2048 : k cast->Kg (swizzled) + k-part gate partials   (2 rows)
// bx <  4096 : q-part gate partials                           (2 rows)
// bx <  8192 : v transpose->Vg (swizzled) + v-part gate partials (32x32 tile)
// Kg tile [bh][jt][32x256]: (r,d) at r*256 + (d ^ ((r&7)<<3)).
// Vg tile [bh][jt][256x32]: (d,j) at d*32 + (j ^ (((d>>1)&3)<<3)).
// Gate partials accumulate into igA/fgA (zeroed) via unsafeAtomicAdd.
__global__ __launch_bounds__(256) void prep_kernel(
    const float* __restrict__ q, const float* __restrict__ k, const float* __restrict__ v,
    const float* __restrict__ wi, const float* __restrict__ wf,
    short* __restrict__ Kg, short* __restrict__ Vg,
    float* __restrict__ igA, float* __restrict__ fgA) {
  __shared__ short vtile[32][33];
  const int bx = blockIdx.x, t = threadIdx.x;
  if (bx < 4096) {
    const bool isk = (bx < 2048);
    const int g_row = (bx & 2047) * 2 + (t >> 7);
    const int col = (t & 127) * 8;
    const float* src = (isk ? k : q) + (long)g_row*HID + col;
    const f32x4 x0 = *(const f32x4*)src;
    const f32x4 x1 = *(const f32x4*)(src + 4);
    const int wrow = (isk ? HID : 0) + col;
    f32x4 ai = {0.f,0.f,0.f,0.f}, af = {0.f,0.f,0.f,0.f};
#pragma unroll
    for (int j = 0; j < 4; j++) {
      ai += x0[j] * *(const f32x4*)(wi + (long)(wrow + j)*4);
      af += x0[j] * *(const f32x4*)(wf + (long)(wrow + j)*4);
    }
#pragma unroll
    for (int j = 0; j < 4; j++) {
      ai += x1[j] * *(const f32x4*)(wi + (long)(wrow + 4 + j)*4);
      af += x1[j] * *(const f32x4*)(wf + (long)(wrow + 4 + j)*4);
    }
    if (isk) {
      bf16x8 o = pack8(x0, x1);
      const int b = g_row >> 11, s = g_row & (S_LEN-1);
      const int hh = col >> 8, d = col & 255;
      const int bh = b*NHEAD + hh, jt = s >> 5, rr = s & 31;
      *(bf16x8*)(Kg + ((long)bh*64 + jt)*8192 + rr*256 + (d ^ ((rr & 7) << 3))) = o;
    }
    for (int mk = 32; mk >= 1; mk >>= 1) {
#pragma unroll
      for (int e = 0; e < 4; e++) {
        ai[e] += __shfl_xor(ai[e], mk);
        af[e] += __shfl_xor(af[e], mk);
      }
    }
    if ((t & 63) == 0) {
#pragma unroll
      for (int e = 0; e < 4; e++) {
        unsafeAtomicAdd(&igA[(long)g_row*NHEAD + e], ai[e]);
        unsafeAtomicAdd(&fgA[(long)g_row*NHEAD + e], af[e]);
      }
    }
  } else {
    const int t2 = bx - 4096;
    const int d0 = (t2 & 7) * 32, j0 = ((t2 >> 3) & 63) * 32, bhv = t2 >> 9;
    const int b = bhv >> 2, hh = bhv & 3;
    const int c = t & 31, rr = t >> 5;
    const int wrow = 2*HID + hh*DHD + d0 + c;
    const f32x4 wiv = *(const f32x4*)(wi + (long)wrow*4);
    const f32x4 wfv = *(const f32x4*)(wf + (long)wrow*4);
#pragma unroll
    for (int kk = 0; kk < 32; kk += 8) {
      const int row = b*S_LEN + j0 + rr + kk;
      const float xv = v[(long)row*HID + hh*DHD + d0 + c];
      vtile[rr + kk][c] = f2b(xv);
      f32x4 pi = xv * wiv, pf = xv * wfv;
      for (int mk = 16; mk >= 1; mk >>= 1) {
#pragma unroll
        for (int e = 0; e < 4; e++) {
          pi[e] += __shfl_xor(pi[e], mk);
          pf[e] += __shfl_xor(pf[e], mk);
        }
      }
      if (c == 0) {
#pragma unroll
        for (int e = 0; e < 4; e++) {
          unsafeAtomicAdd(&igA[(long)row*NHEAD + e], pi[e]);
          unsafeAtomicAdd(&fgA[(long)row*NHEAD + e], pf[e]);
        }
      }
    }
    __syncthreads();
    const long base = ((long)bhv*64 + (j0 >> 5)) * 8192;
#pragma unroll
    for (int kk = 0; kk < 32; kk += 8) {
      const int d = d0 + rr + kk;
      Vg[base + (long)d*32 + (c ^ (((d >> 1) & 3) << 3))] = vtile[c][rr + kk];
    }
  }
}

// ---- kernel 2: per-(b,h) scan (parallel Hillis-Steele); adds gate biases ----
__global__ void scan_kernel(const float* __restrict__ ig, const float* __restrict__ fg,
                            const float* __restrict__ bi, const float* __restrict__ bf_,
                            float* __restrict__ a_out, float* __restrict__ m_out,
                            float* __restrict__ nf_out) {
  int bh = blockIdx.x, b = bh >> 2, h = bh & 3;
  int t = threadIdx.x;
  __shared__ float tot[256];
  long gbase = (long)b * S_LEN;
  const float biv = bi[h], bfv = bf_[h];
  float ls[8];
  float run = 0.f;
  for (int e = 0; e < 8; e++) {
    int s = t*8 + e;
    float x = fg[(gbase + s)*NHEAD + h] + bfv;
    float l = fminf(x, 0.f) - log1pf(expf(-fabsf(x)));  // stable log_sigmoid
    run += l; ls[e] = run;
  }
  tot[t] = run;
  __syncthreads();
  for (int off = 1; off < 256; off <<= 1) {
    float x = tot[t];
    if (t >= off) x += tot[t - off];
    __syncthreads();
    tot[t] = x;
    __syncthreads();
  }
  float offc = (t == 0) ? 0.f : tot[t-1];
  __syncthreads();
  float av[8], am[8], csv[8];
  float runm = -1e30f;
  for (int e = 0; e < 8; e++) {
    int s = t*8 + e;
    float cs = ls[e] + offc;
    csv[e] = cs;
    float a = (ig[(gbase + s)*NHEAD + h] + biv) - cs;
    av[e] = a;
    runm = fmaxf(runm, a);
    am[e] = runm;
  }
  tot[t] = runm;
  __syncthreads();
  for (int off = 1; off < 256; off <<= 1) {
    float x = tot[t];
    if (t >= off) x = fmaxf(x, tot[t - off]);
    __syncthreads();
    tot[t] = x;
    __syncthreads();
  }
  float offm = (t == 0) ? -1e30f : tot[t-1];
  long obase = (long)bh * S_LEN;
  for (int e = 0; e < 8; e++) {
    int s = t*8 + e;
    float mm = fmaxf(am[e], offm);
    a_out[obase + s]  = av[e];
    m_out[obase + s]  = mm;
    nf_out[obase + s] = expf(-(csv[e] + mm));
  }
}

// ---- kernel 3: main. 256 blocks = (bh, it). 4 waves = 2 rg2 x 2 kp. ----
__global__ __launch_bounds__(256, 1) void mlstm_main_kernel(
    const float* __restrict__ q, const short* __restrict__ Kg, const short* __restrict__ Vg,
    const float* __restrict__ a_arr, const float* __restrict__ m_arr,
    const float* __restrict__ nf_arr, const float* __restrict__ lns,
    float* __restrict__ outp) {
  __shared__ alignas(16) short Kst[2][2][8192];   // [dbuf][parity][32k x 256d swz]
  __shared__ alignas(16) short Vst[2][2][8192];   // [dbuf][parity][256d x 32j swz]
  __shared__ alignas(16) short plds[4][16*36];
  const int w = threadIdx.x >> 6, lane = threadIdx.x & 63;
  const int lr = lane & 15, g = lane >> 4;
  const int rg2 = w >> 1, kp = w & 1;
  const int bh = blockIdx.x & 7, it = blockIdx.x >> 3;
  const int b = bh >> 2, h = bh & 3;
  const int R0 = it*64 + rg2*32;          // wave's first global row
  const long arow = (long)bh * S_LEN;
  const int np = it + 1;                  // periods (2 tiles each)
  const int ntw = it*2 + rg2 + 1;         // wave computes jt < ntw (parity kp)
  const f32x4 zz = {0.f,0.f,0.f,0.f};
  const int sw = (lr & 7) << 3;

  // Q fragments for the wave's 32 rows, cast inline from fp32 source
  bf16x8 qfa[8], qfb[8];
  const float* qsrc = q + ((long)(b*S_LEN + R0 + lr))*HID + h*DHD + g*8;
#pragma unroll
  for (int c8 = 0; c8 < 8; c8++) {
    f32x4 u0 = *(const f32x4*)(qsrc + c8*32);
    f32x4 u1 = *(const f32x4*)(qsrc + c8*32 + 4);
    f32x4 w0 = *(const f32x4*)(qsrc + 16*HID + c8*32);
    f32x4 w1 = *(const f32x4*)(qsrc + 16*HID + c8*32 + 4);
    qfa[c8] = pack8(u0, u1);
    qfb[c8] = pack8(w0, w1);
  }
  float ma[4], mb[4];
#pragma unroll
  for (int r = 0; r < 4; r++) {
    ma[r] = m_arr[arow + R0 + g*4 + r];
    mb[r] = m_arr[arow + R0 + 16 + g*4 + r];
  }

  f32x4 oa[16], ob[16];
#pragma unroll
  for (int t = 0; t < 16; t++) { oa[t] = zz; ob[t] = zz; }
  float rs_a[4] = {0,0,0,0}, rs_b[4] = {0,0,0,0};
  short* myp = plds[w];

  // wave w stages one 16KB tile-buffer per period: w<2 -> K parity w, else V.
  auto STAGE = [&](int pb, int p) {
    const int jts = 2*p + (w & 1);
    short* dst = (w < 2) ? &Kst[pb][w & 1][0] : &Vst[pb][w & 1][0];
    const short* src = ((w < 2) ? Kg : Vg) + ((long)bh*64 + jts)*8192 + lane*8;
#pragma unroll
    for (int u = 0; u < 16; u++)
      gload16(src + u*512, dst + u*512);
  };

  float aC0, aC1, aN0 = 0.f, aN1 = 0.f;
  STAGE(0, 0);
  { const int j0 = kp*32;
    aC0 = a_arr[arow + j0 + lr]; aC1 = a_arr[arow + j0 + 16 + lr]; }

  for (int p = 0; p < np; ++p) {
    const int pb = p & 1;
    if (p + 1 < np) {
      STAGE(pb ^ 1, p + 1);
      { const int j0 = (2*(p+1) + kp)*32;
        aN0 = a_arr[arow + j0 + lr]; aN1 = a_arr[arow + j0 + 16 + lr]; }
      asm volatile("s_waitcnt vmcnt(16)" ::: "memory");  // own 16 DMA of tile p done
    } else {
      asm volatile("s_waitcnt vmcnt(0)" ::: "memory");
    }
    __builtin_amdgcn_s_barrier();

    const int jtc = 2*p + kp;
    if (jtc < ntw) {
      const int j0 = jtc*32;
      const short* Kt = &Kst[pb][kp][0];
      const short* Vt = &Vst[pb][kp][0];
      f32x4 s0a = zz, s1a = zz, s0b = zz, s1b = zz;
      __builtin_amdgcn_s_setprio(1);
#pragma unroll
      for (int c8 = 0; c8 < 8; c8++) {
        const int ko = lr*256 + ((c8*32 + g*8) ^ sw);
        bf16x8 k0 = *(const bf16x8*)&Kt[ko];
        bf16x8 k1 = *(const bf16x8*)&Kt[ko + 4096];
        s0a = __builtin_amdgcn_mfma_f32_16x16x32_bf16(qfa[c8], k0, s0a, 0, 0, 0);
        s0b = __builtin_amdgcn_mfma_f32_16x16x32_bf16(qfb[c8], k0, s0b, 0, 0, 0);
        s1a = __builtin_amdgcn_mfma_f32_16x16x32_bf16(qfa[c8], k1, s1a, 0, 0, 0);
        s1b = __builtin_amdgcn_mfma_f32_16x16x32_bf16(qfb[c8], k1, s1b, 0, 0, 0);
      }
      __builtin_amdgcn_s_setprio(0);
      // ---- group a: P + re-fragment ----
      bf16x8 pa_a, pa_b;
      {
        const bool needmask = (j0 + 31 > R0);
#pragma unroll
        for (int r = 0; r < 4; r++) {
          const int i = R0 + g*4 + r;
          float p0 = s0a[r] * 0.0625f * __expf(aC0 - ma[r]);
          float p1 = s1a[r] * 0.0625f * __expf(aC1 - ma[r]);
          if (needmask) {
            if (j0 + lr > i)      p0 = 0.f;
            if (j0 + 16 + lr > i) p1 = 0.f;
          }
          rs_a[r] += p0 + p1;
          myp[(g*4 + r)*36 + lr]      = f2b(p0);
          myp[(g*4 + r)*36 + 16 + lr] = f2b(p1);
        }
        const short* rp = myp + lr*36 + g*8;
        short4v plo = *(const short4v*)rp;
        short4v phi = *(const short4v*)(rp + 4);
        pa_a = bf16x8{plo[0],plo[1],plo[2],plo[3],phi[0],phi[1],phi[2],phi[3]};
      }
      // ---- group b ----
      {
        const bool needmask = (j0 + 31 > R0 + 16);
#pragma unroll
        for (int r = 0; r < 4; r++) {
          const int i = R0 + 16 + g*4 + r;
          float p0 = s0b[r] * 0.0625f * __expf(aC0 - mb[r]);
          float p1 = s1b[r] * 0.0625f * __expf(aC1 - mb[r]);
          if (needmask) {
            if (j0 + lr > i)      p0 = 0.f;
            if (j0 + 16 + lr > i) p1 = 0.f;
          }
          rs_b[r] += p0 + p1;
          myp[(g*4 + r)*36 + lr]      = f2b(p0);
          myp[(g*4 + r)*36 + 16 + lr] = f2b(p1);
        }
        const short* rp = myp + lr*36 + g*8;
        short4v plo = *(const short4v*)rp;
        short4v phi = *(const short4v*)(rp + 4);
        pa_b = bf16x8{plo[0],plo[1],plo[2],plo[3],phi[0],phi[1],phi[2],phi[3]};
      }
      // ---- PV: read each V fragment ONCE, feed both row groups ----
      __builtin_amdgcn_s_setprio(1);
#pragma unroll
      for (int t = 0; t < 16; t++) {
        const int d = t*16 + lr;
        const int vo = d*32 + ((g*8) ^ (((d >> 1) & 3) << 3));
        bf16x8 vf = *(const bf16x8*)&Vt[vo];
        oa[t] = __builtin_amdgcn_mfma_f32_16x16x32_bf16(pa_a, vf, oa[t], 0, 0, 0);
        ob[t] = __builtin_amdgcn_mfma_f32_16x16x32_bf16(pa_b, vf, ob[t], 0, 0, 0);
      }
      __builtin_amdgcn_s_setprio(0);
    }
    __builtin_amdgcn_s_barrier();
    if (p + 1 < np) { aC0 = aN0; aC1 = aN1; }
  }

  // ---- rowsum reduce over the 16 key-columns ----
#pragma unroll
  for (int r = 0; r < 4; r++)
    for (int mk = 1; mk < 16; mk <<= 1) {
      rs_a[r] += __shfl_xor(rs_a[r], mk);
      rs_b[r] += __shfl_xor(rs_b[r], mk);
    }

  // ---- combine key-parities via LDS (kp=1 writes, kp=0 reduces + LN) ----
  float* Ols = (float*)&Kst[0][0][0];   // 64 rows x 256 d fp32 = 64 KB
  float* rsl = (float*)&Vst[0][0][0];   // 64 rowsums
  __syncthreads();
  if (kp == 1) {
#pragma unroll
    for (int r = 0; r < 4; r++) {
      const int rla = rg2*32 + g*4 + r, rlb = rla + 16;
#pragma unroll
      for (int t = 0; t < 16; t++) {
        Ols[(long)rla*256 + t*16 + lr] = oa[t][r];
        Ols[(long)rlb*256 + t*16 + lr] = ob[t][r];
      }
      if (lr == 0) { rsl[rla] = rs_a[r]; rsl[rlb] = rs_b[r]; }
    }
  }
  __syncthreads();
  if (kp == 0) {
    float sc[16];
#pragma unroll
    for (int t = 0; t < 16; t++) sc[t] = lns[h*DHD + t*16 + lr];
    for (int grp = 0; grp < 2; grp++) {
      f32x4* acc = grp ? ob : oa;
      float* rsv = grp ? rs_b : rs_a;
#pragma unroll
      for (int r = 0; r < 4; r++) {
        const int rl = rg2*32 + grp*16 + g*4 + r;
        const int i = R0 + grp*16 + g*4 + r;
        const float rst = rsv[r] + rsl[rl];
        const float nfv = nf_arr[arow + i];
        const float inv = 1.f / (fmaxf(fabsf(rst), nfv) + 1e-6f);
        float sum = 0.f, sq = 0.f;
        float xv[16];
#pragma unroll
        for (int t = 0; t < 16; t++) {
          float x = (acc[t][r] + Ols[(long)rl*256 + t*16 + lr]) * inv;
          xv[t] = x; sum += x; sq += x*x;
        }
        for (int mk = 1; mk < 16; mk <<= 1) {
          sum += __shfl_xor(sum, mk);
          sq  += __shfl_xor(sq,  mk);
        }
        const float mean = sum * (1.f/256.f);
        const float var  = sq * (1.f/256.f) - mean*mean;
        const float rstd = rsqrtf(var + 1e-5f);
        float* orow = outp + ((long)(b*S_LEN + i))*HID + h*DHD + lr;
#pragma unroll
        for (int t = 0; t < 16; t++)
          orow[t*16] = (xv[t] - mean) * rstd * sc[t];
      }
    }
  }
}

extern "C" void kernel_launch(void* const* d_in, const int* in_sizes, int n_in,
                              void* d_out, int out_size, void* d_ws, size_t ws_size,
                              hipStream_t stream) {
  const float* q   = (const float*)d_in[0];
  const float* k   = (const float*)d_in[1];
  const float* v   = (const float*)d_in[2];
  const float* wi  = (const float*)d_in[3];
  const float* bi  = (const float*)d_in[4];
  const float* wf  = (const float*)d_in[5];
  const float* bf_ = (const float*)d_in[6];
  const float* lns = (const float*)d_in[7];
  float* outp = (float*)d_out;

  char* ws = (char*)d_ws;
  const long nelem = (long)BH_CNT * S_LEN * DHD;      // 4,194,304
  short* Kg  = (short*)ws;
  short* Vg  = Kg + nelem;
  float* igA = (float*)(ws + 2*nelem*sizeof(short));
  float* fgA = igA + (long)BATCH*S_LEN*NHEAD;
  float* aA  = fgA + (long)BATCH*S_LEN*NHEAD;
  float* mA  = aA + (long)BH_CNT*S_LEN;
  float* nfA = mA + (long)BH_CNT*S_LEN;

  // zero the gate accumulators (igA and fgA are contiguous)
  hipMemsetAsync(igA, 0, 2 * (size_t)BATCH*S_LEN*NHEAD * sizeof(float), stream);

  prep_kernel<<<8192, 256, 0, stream>>>(q, k, v, wi, wf, Kg, Vg, igA, fgA);
  scan_kernel<<<BH_CNT, 256, 0, stream>>>(igA, fgA, bi, bf_, aA, mA, nfA);
  mlstm_main_kernel<<<BH_CNT*32, 256, 0, stream>>>(q, Kg, Vg, aA, mA, nfA, lns, outp);
}

// Round 9
// 156.616 us; speedup vs baseline: 2.6160x; 1.0341x over previous
//
#include <hip/hip_runtime.h>
#include <hip/hip_bf16.h>

// mLSTM parallel-stabilized cell, MI355X (gfx950).
// B=2, S=2048, H=1024, NH=4, DH=256.
// Identity: max_log_D[i] = cs[i] + m[i], m[i] = prefixmax(ig[j]-cs[j]);
// D[i][j] = exp(a[j]-m[i]), a[j] = ig[j]-cs[j], exponent always <= 0.
// R9: main+scan reverted VERBATIM to R6 (last passing, absmax 0.0906).
// Prep only: merged gate block computes q+k+v gate partials in-register
// (2 atomics/row/matrix), v-transpose branch is now gate-free. Grid 6144.

#define S_LEN 2048
#define DHD   256
#define NHEAD 4
#define BATCH 2
#define HID   1024
#define BH_CNT (BATCH*NHEAD)

typedef __attribute__((ext_vector_type(8))) short bf16x8;
typedef __attribute__((ext_vector_type(4))) short short4v;
typedef __attribute__((ext_vector_type(4))) float f32x4;

static __device__ __forceinline__ short f2b(float f) {
  __hip_bfloat16 h = __float2bfloat16(f);
  return *reinterpret_cast<short*>(&h);
}

static __device__ __forceinline__ bf16x8 pack8(f32x4 a, f32x4 b) {
  bf16x8 o;
  o[0]=f2b(a[0]); o[1]=f2b(a[1]); o[2]=f2b(a[2]); o[3]=f2b(a[3]);
  o[4]=f2b(b[0]); o[5]=f2b(b[1]); o[6]=f2b(b[2]); o[7]=f2b(b[3]);
  return o;
}

// async global->LDS DMA, 16B/lane. ldsdst wave-uniform; lane l -> dst + l*16B.
static __device__ __forceinline__ void gload16(const void* src, void* ldsdst) {
  __builtin_amdgcn_global_load_lds(
      (const __attribute__((address_space(1))) void*)src,
      (__attribute__((address_space(3))) void*)ldsdst, 16, 0, 0);
}

// ---- kernel 1 (prep): grid 6144 x 256.
// bx <  2048 : merged gates (q+k+v parts, 2 rows) + k cast->Kg (swizzled)
// bx <  6144 : v transpose->Vg (swizzled), gate-free
// Kg tile [bh][jt][32x256]: (r,d) at r*256 + (d ^ ((r&7)<<3)).
// Vg tile [bh][jt][256x32]: (d,j) at d*32 + (j ^ (((d>>1)&3)<<3)).
// Gate partials accumulate into igA/fgA (zeroed) via unsafeAtomicAdd.
__global__ __launch_bounds__(256) void prep_kernel(
    const float* __restrict__ q, const float* __restrict__ k, const float* __restrict__ v,
    const float* __restrict__ wi, const float* __restrict__ wf,
    short* __restrict__ Kg, short* __restrict__ Vg,
    float* __restrict__ igA, float* __restrict__ fgA) {
  __shared__ short vtile[32][33];
  const int bx = blockIdx.x, t = threadIdx.x;
  if (bx < 2048) {
    const int g_row = bx * 2 + (t >> 7);
    const int col = (t & 127) * 8;
    const long off = (long)g_row*HID + col;
    const f32x4 xq0 = *(const f32x4*)(q + off);
    const f32x4 xq1 = *(const f32x4*)(q + off + 4);
    const f32x4 xk0 = *(const f32x4*)(k + off);
    const f32x4 xk1 = *(const f32x4*)(k + off + 4);
    const f32x4 xv0 = *(const f32x4*)(v + off);
    const f32x4 xv1 = *(const f32x4*)(v + off + 4);
    f32x4 ai = {0.f,0.f,0.f,0.f}, af = {0.f,0.f,0.f,0.f};
#pragma unroll
    for (int j = 0; j < 4; j++) {
      // q part (wrow = col), k part (wrow = HID+col), v part (wrow = 2*HID+col)
      ai += xq0[j] * *(const f32x4*)(wi + (long)(col + j)*4);
      af += xq0[j] * *(const f32x4*)(wf + (long)(col + j)*4);
      ai += xq1[j] * *(const f32x4*)(wi + (long)(col + 4 + j)*4);
      af += xq1[j] * *(const f32x4*)(wf + (long)(col + 4 + j)*4);
      ai += xk0[j] * *(const f32x4*)(wi + (long)(HID + col + j)*4);
      af += xk0[j] * *(const f32x4*)(wf + (long)(HID + col + j)*4);
      ai += xk1[j] * *(const f32x4*)(wi + (long)(HID + col + 4 + j)*4);
      af += xk1[j] * *(const f32x4*)(wf + (long)(HID + col + 4 + j)*4);
      ai += xv0[j] * *(const f32x4*)(wi + (long)(2*HID + col + j)*4);
      af += xv0[j] * *(const f32x4*)(wf + (long)(2*HID + col + j)*4);
      ai += xv1[j] * *(const f32x4*)(wi + (long)(2*HID + col + 4 + j)*4);
      af += xv1[j] * *(const f32x4*)(wf + (long)(2*HID + col + 4 + j)*4);
    }
    {
      // k cast -> Kg (swizzled), same bytes as R6
      bf16x8 o = pack8(xk0, xk1);
      const int b = g_row >> 11, s = g_row & (S_LEN-1);
      const int hh = col >> 8, d = col & 255;
      const int bh = b*NHEAD + hh, jt = s >> 5, rr = s & 31;
      *(bf16x8*)(Kg + ((long)bh*64 + jt)*8192 + rr*256 + (d ^ ((rr & 7) << 3))) = o;
    }
    for (int mk = 32; mk >= 1; mk >>= 1) {
#pragma unroll
      for (int e = 0; e < 4; e++) {
        ai[e] += __shfl_xor(ai[e], mk);
        af[e] += __shfl_xor(af[e], mk);
      }
    }
    if ((t & 63) == 0) {
#pragma unroll
      for (int e = 0; e < 4; e++) {
        unsafeAtomicAdd(&igA[(long)g_row*NHEAD + e], ai[e]);
        unsafeAtomicAdd(&fgA[(long)g_row*NHEAD + e], af[e]);
      }
    }
  } else {
    // ---- pure v transpose -> Vg (swizzled tiles) ----
    const int t2 = bx - 2048;
    const int d0 = (t2 & 7) * 32, j0 = ((t2 >> 3) & 63) * 32, bhv = t2 >> 9;
    const int b = bhv >> 2, hh = bhv & 3;
    const int c = t & 31, rr = t >> 5;
#pragma unroll
    for (int kk = 0; kk < 32; kk += 8)
      vtile[rr + kk][c] = f2b(v[((long)(b*S_LEN + j0 + rr + kk))*HID + hh*DHD + d0 + c]);
    __syncthreads();
    const long base = ((long)bhv*64 + (j0 >> 5)) * 8192;
#pragma unroll
    for (int kk = 0; kk < 32; kk += 8) {
      const int d = d0 + rr + kk;
      Vg[base + (long)d*32 + (c ^ (((d >> 1) & 3) << 3))] = vtile[c][rr + kk];
    }
  }
}

// ---- kernel 2: per-(b,h) scan (parallel Hillis-Steele); adds gate biases ----
// (verbatim R6)
__global__ void scan_kernel(const float* __restrict__ ig, const float* __restrict__ fg,
                            const float* __restrict__ bi, const float* __restrict__ bf_,
                            float* __restrict__ a_out, float* __restrict__ m_out,
                            float* __restrict__ nf_out) {
  int bh = blockIdx.x, b = bh >> 2, h = bh & 3;
  int t = threadIdx.x;
  __shared__ float tot[256];
  long gbase = (long)b * S_LEN;
  const float biv = bi[h], bfv = bf_[h];
  float ls[8];
  float run = 0.f;
  for (int e = 0; e < 8; e++) {
    int s = t*8 + e;
    float x = fg[(gbase + s)*NHEAD + h] + bfv;
    float l = fminf(x, 0.f) - log1pf(expf(-fabsf(x)));  // stable log_sigmoid
    run += l; ls[e] = run;
  }
  tot[t] = run;
  __syncthreads();
  for (int off = 1; off < 256; off <<= 1) {
    float x = tot[t];
    if (t >= off) x += tot[t - off];
    __syncthreads();
    tot[t] = x;
    __syncthreads();
  }
  float offc = (t == 0) ? 0.f : tot[t-1];
  __syncthreads();
  float av[8], am[8], csv[8];
  float runm = -1e30f;
  for (int e = 0; e < 8; e++) {
    int s = t*8 + e;
    float cs = ls[e] + offc;
    csv[e] = cs;
    float a = (ig[(gbase + s)*NHEAD + h] + biv) - cs;
    av[e] = a;
    runm = fmaxf(runm, a);
    am[e] = runm;
  }
  tot[t] = runm;
  __syncthreads();
  for (int off = 1; off < 256; off <<= 1) {
    float x = tot[t];
    if (t >= off) x = fmaxf(x, tot[t - off]);
    __syncthreads();
    tot[t] = x;
    __syncthreads();
  }
  float offm = (t == 0) ? -1e30f : tot[t-1];
  long obase = (long)bh * S_LEN;
  for (int e = 0; e < 8; e++) {
    int s = t*8 + e;
    float mm = fmaxf(am[e], offm);
    a_out[obase + s]  = av[e];
    m_out[obase + s]  = mm;
    nf_out[obase + s] = expf(-(csv[e] + mm));
  }
}

// ---- kernel 3: main (verbatim R6, last passing). 256 blocks = (bh, it).
// 4 waves = 2 rg2 x 2 kp; dbuf LDS staging w/ counted vmcnt; parity combine.
__global__ __launch_bounds__(256, 1) void mlstm_main_kernel(
    const float* __restrict__ q, const short* __restrict__ Kg, const short* __restrict__ Vg,
    const float* __restrict__ a_arr, const float* __restrict__ m_arr,
    const float* __restrict__ nf_arr, const float* __restrict__ lns,
    float* __restrict__ outp) {
  __shared__ alignas(16) short Kst[2][2][8192];   // [dbuf][parity][32k x 256d swz]
  __shared__ alignas(16) short Vst[2][2][8192];   // [dbuf][parity][256d x 32j swz]
  __shared__ alignas(16) short plds[4][16*36];
  const int w = threadIdx.x >> 6, lane = threadIdx.x & 63;
  const int lr = lane & 15, g = lane >> 4;
  const int rg2 = w >> 1, kp = w & 1;
  const int bh = blockIdx.x & 7, it = blockIdx.x >> 3;
  const int b = bh >> 2, h = bh & 3;
  const int R0 = it*64 + rg2*32;          // wave's first global row
  const long arow = (long)bh * S_LEN;
  const int np = it + 1;                  // periods (2 tiles each)
  const int ntw = it*2 + rg2 + 1;         // wave computes jt < ntw (parity kp)
  const f32x4 zz = {0.f,0.f,0.f,0.f};
  const int sw = (lr & 7) << 3;

  // Q fragments for the wave's 32 rows, cast inline from fp32 source
  bf16x8 qfa[8], qfb[8];
  const float* qsrc = q + ((long)(b*S_LEN + R0 + lr))*HID + h*DHD + g*8;
#pragma unroll
  for (int c8 = 0; c8 < 8; c8++) {
    f32x4 u0 = *(const f32x4*)(qsrc + c8*32);
    f32x4 u1 = *(const f32x4*)(qsrc + c8*32 + 4);
    f32x4 w0 = *(const f32x4*)(qsrc + 16*HID + c8*32);
    f32x4 w1 = *(const f32x4*)(qsrc + 16*HID + c8*32 + 4);
    qfa[c8] = pack8(u0, u1);
    qfb[c8] = pack8(w0, w1);
  }
  float ma[4], mb[4];
#pragma unroll
  for (int r = 0; r < 4; r++) {
    ma[r] = m_arr[arow + R0 + g*4 + r];
    mb[r] = m_arr[arow + R0 + 16 + g*4 + r];
  }

  f32x4 oa[16], ob[16];
#pragma unroll
  for (int t = 0; t < 16; t++) { oa[t] = zz; ob[t] = zz; }
  float rs_a[4] = {0,0,0,0}, rs_b[4] = {0,0,0,0};
  short* myp = plds[w];

  // wave w stages one 16KB tile-buffer per period: w<2 -> K parity w, else V.
  auto STAGE = [&](int pb, int p) {
    const int jts = 2*p + (w & 1);
    short* dst = (w < 2) ? &Kst[pb][w & 1][0] : &Vst[pb][w & 1][0];
    const short* src = ((w < 2) ? Kg : Vg) + ((long)bh*64 + jts)*8192 + lane*8;
#pragma unroll
    for (int u = 0; u < 16; u++)
      gload16(src + u*512, dst + u*512);
  };

  float aC0, aC1, aN0 = 0.f, aN1 = 0.f;
  STAGE(0, 0);
  { const int j0 = kp*32;
    aC0 = a_arr[arow + j0 + lr]; aC1 = a_arr[arow + j0 + 16 + lr]; }

  for (int p = 0; p < np; ++p) {
    const int pb = p & 1;
    if (p + 1 < np) {
      STAGE(pb ^ 1, p + 1);
      { const int j0 = (2*(p+1) + kp)*32;
        aN0 = a_arr[arow + j0 + lr]; aN1 = a_arr[arow + j0 + 16 + lr]; }
      asm volatile("s_waitcnt vmcnt(16)" ::: "memory");  // own 16 DMA of tile p done
    } else {
      asm volatile("s_waitcnt vmcnt(0)" ::: "memory");
    }
    __builtin_amdgcn_s_barrier();

    const int jtc = 2*p + kp;
    if (jtc < ntw) {
      const int j0 = jtc*32;
      const short* Kt = &Kst[pb][kp][0];
      const short* Vt = &Vst[pb][kp][0];
      f32x4 s0a = zz, s1a = zz, s0b = zz, s1b = zz;
      __builtin_amdgcn_s_setprio(1);
#pragma unroll
      for (int c8 = 0; c8 < 8; c8++) {
        const int ko = lr*256 + ((c8*32 + g*8) ^ sw);
        bf16x8 k0 = *(const bf16x8*)&Kt[ko];
        bf16x8 k1 = *(const bf16x8*)&Kt[ko + 4096];
        s0a = __builtin_amdgcn_mfma_f32_16x16x32_bf16(qfa[c8], k0, s0a, 0, 0, 0);
        s0b = __builtin_amdgcn_mfma_f32_16x16x32_bf16(qfb[c8], k0, s0b, 0, 0, 0);
        s1a = __builtin_amdgcn_mfma_f32_16x16x32_bf16(qfa[c8], k1, s1a, 0, 0, 0);
        s1b = __builtin_amdgcn_mfma_f32_16x16x32_bf16(qfb[c8], k1, s1b, 0, 0, 0);
      }
      __builtin_amdgcn_s_setprio(0);
      // ---- group a: P + re-fragment ----
      bf16x8 pa_a, pa_b;
      {
        const bool needmask = (j0 + 31 > R0);
#pragma unroll
        for (int r = 0; r < 4; r++) {
          const int i = R0 + g*4 + r;
          float p0 = s0a[r] * 0.0625f * __expf(aC0 - ma[r]);
          float p1 = s1a[r] * 0.0625f * __expf(aC1 - ma[r]);
          if (needmask) {
            if (j0 + lr > i)      p0 = 0.f;
            if (j0 + 16 + lr > i) p1 = 0.f;
          }
          rs_a[r] += p0 + p1;
          myp[(g*4 + r)*36 + lr]      = f2b(p0);
          myp[(g*4 + r)*36 + 16 + lr] = f2b(p1);
        }
        const short* rp = myp + lr*36 + g*8;
        short4v plo = *(const short4v*)rp;
        short4v phi = *(const short4v*)(rp + 4);
        pa_a = bf16x8{plo[0],plo[1],plo[2],plo[3],phi[0],phi[1],phi[2],phi[3]};
      }
      // ---- group b ----
      {
        const bool needmask = (j0 + 31 > R0 + 16);
#pragma unroll
        for (int r = 0; r < 4; r++) {
          const int i = R0 + 16 + g*4 + r;
          float p0 = s0b[r] * 0.0625f * __expf(aC0 - mb[r]);
          float p1 = s1b[r] * 0.0625f * __expf(aC1 - mb[r]);
          if (needmask) {
            if (j0 + lr > i)      p0 = 0.f;
            if (j0 + 16 + lr > i) p1 = 0.f;
          }
          rs_b[r] += p0 + p1;
          myp[(g*4 + r)*36 + lr]      = f2b(p0);
          myp[(g*4 + r)*36 + 16 + lr] = f2b(p1);
        }
        const short* rp = myp + lr*36 + g*8;
        short4v plo = *(const short4v*)rp;
        short4v phi = *(const short4v*)(rp + 4);
        pa_b = bf16x8{plo[0],plo[1],plo[2],plo[3],phi[0],phi[1],phi[2],phi[3]};
      }
      // ---- PV: read each V fragment ONCE, feed both row groups ----
      __builtin_amdgcn_s_setprio(1);
#pragma unroll
      for (int t = 0; t < 16; t++) {
        const int d = t*16 + lr;
        const int vo = d*32 + ((g*8) ^ (((d >> 1) & 3) << 3));
        bf16x8 vf = *(const bf16x8*)&Vt[vo];
        oa[t] = __builtin_amdgcn_mfma_f32_16x16x32_bf16(pa_a, vf, oa[t], 0, 0, 0);
        ob[t] = __builtin_amdgcn_mfma_f32_16x16x32_bf16(pa_b, vf, ob[t], 0, 0, 0);
      }
      __builtin_amdgcn_s_setprio(0);
    }
    __builtin_amdgcn_s_barrier();
    if (p + 1 < np) { aC0 = aN0; aC1 = aN1; }
  }

  // ---- rowsum reduce over the 16 key-columns ----
#pragma unroll
  for (int r = 0; r < 4; r++)
    for (int mk = 1; mk < 16; mk <<= 1) {
      rs_a[r] += __shfl_xor(rs_a[r], mk);
      rs_b[r] += __shfl_xor(rs_b[r], mk);
    }

  // ---- combine key-parities via LDS (kp=1 writes, kp=0 reduces + LN) ----
  float* Ols = (float*)&Kst[0][0][0];   // 64 rows x 256 d fp32 = 64 KB
  float* rsl = (float*)&Vst[0][0][0];   // 64 rowsums
  __syncthreads();
  if (kp == 1) {
#pragma unroll
    for (int r = 0; r < 4; r++) {
      const int rla = rg2*32 + g*4 + r, rlb = rla + 16;
#pragma unroll
      for (int t = 0; t < 16; t++) {
        Ols[(long)rla*256 + t*16 + lr] = oa[t][r];
        Ols[(long)rlb*256 + t*16 + lr] = ob[t][r];
      }
      if (lr == 0) { rsl[rla] = rs_a[r]; rsl[rlb] = rs_b[r]; }
    }
  }
  __syncthreads();
  if (kp == 0) {
    float sc[16];
#pragma unroll
    for (int t = 0; t < 16; t++) sc[t] = lns[h*DHD + t*16 + lr];
    for (int grp = 0; grp < 2; grp++) {
      f32x4* acc = grp ? ob : oa;
      float* rsv = grp ? rs_b : rs_a;
#pragma unroll
      for (int r = 0; r < 4; r++) {
        const int rl = rg2*32 + grp*16 + g*4 + r;
        const int i = R0 + grp*16 + g*4 + r;
        const float rst = rsv[r] + rsl[rl];
        const float nfv = nf_arr[arow + i];
        const float inv = 1.f / (fmaxf(fabsf(rst), nfv) + 1e-6f);
        float sum = 0.f, sq = 0.f;
        float xv[16];
#pragma unroll
        for (int t = 0; t < 16; t++) {
          float x = (acc[t][r] + Ols[(long)rl*256 + t*16 + lr]) * inv;
          xv[t] = x; sum += x; sq += x*x;
        }
        for (int mk = 1; mk < 16; mk <<= 1) {
          sum += __shfl_xor(sum, mk);
          sq  += __shfl_xor(sq,  mk);
        }
        const float mean = sum * (1.f/256.f);
        const float var  = sq * (1.f/256.f) - mean*mean;
        const float rstd = rsqrtf(var + 1e-5f);
        float* orow = outp + ((long)(b*S_LEN + i))*HID + h*DHD + lr;
#pragma unroll
        for (int t = 0; t < 16; t++)
          orow[t*16] = (xv[t] - mean) * rstd * sc[t];
      }
    }
  }
}

extern "C" void kernel_launch(void* const* d_in, const int* in_sizes, int n_in,
                              void* d_out, int out_size, void* d_ws, size_t ws_size,
                              hipStream_t stream) {
  const float* q   = (const float*)d_in[0];
  const float* k   = (const float*)d_in[1];
  const float* v   = (const float*)d_in[2];
  const float* wi  = (const float*)d_in[3];
  const float* bi  = (const float*)d_in[4];
  const float* wf  = (const float*)d_in[5];
  const float* bf_ = (const float*)d_in[6];
  const float* lns = (const float*)d_in[7];
  float* outp = (float*)d_out;

  char* ws = (char*)d_ws;
  const long nelem = (long)BH_CNT * S_LEN * DHD;      // 4,194,304
  short* Kg  = (short*)ws;
  short* Vg  = Kg + nelem;
  float* igA = (float*)(ws + 2*nelem*sizeof(short));
  float* fgA = igA + (long)BATCH*S_LEN*NHEAD;
  float* aA  = fgA + (long)BATCH*S_LEN*NHEAD;
  float* mA  = aA + (long)BH_CNT*S_LEN;
  float* nfA = mA + (long)BH_CNT*S_LEN;

  // zero the gate accumulators (igA and fgA are contiguous)
  hipMemsetAsync(igA, 0, 2 * (size_t)BATCH*S_LEN*NHEAD * sizeof(float), stream);

  prep_kernel<<<6144, 256, 0, stream>>>(q, k, v, wi, wf, Kg, Vg, igA, fgA);
  scan_kernel<<<BH_CNT, 256, 0, stream>>>(igA, fgA, bi, bf_, aA, mA, nfA);
  mlstm_main_kernel<<<BH_CNT*32, 256, 0, stream>>>(q, Kg, Vg, aA, mA, nfA, lns, outp);
}